// Round 1
// baseline (344.757 us; speedup 1.0000x reference)
//
#include <hip/hip_runtime.h>
#include <hip/hip_bf16.h>
#include <cstdint>

typedef __attribute__((ext_vector_type(4))) float f32x4;
typedef __attribute__((ext_vector_type(8))) short s16x8;
typedef unsigned short u16;

#define B_  4
#define N_  1024
#define D_  1024
#define H_  16
#define DH_ 64
#define M_  4096      // B_*N_
#define SIXD 6144

__device__ __forceinline__ u16 f2bf(float f) {
    unsigned u = __builtin_bit_cast(unsigned, f);
    unsigned r = (u + 0x7fffu + ((u >> 16) & 1u)) >> 16;
    return (u16)r;
}

__device__ __forceinline__ void gload16(const void* g, void* l) {
    __builtin_amdgcn_global_load_lds((const __attribute__((address_space(1))) void*)g,
                                     (__attribute__((address_space(3))) void*)l,
                                     16, 0, 0);
}

// ---------------- weight convert+transpose: in[R][C] f32 -> out[C][R] bf16 ---------
__global__ __launch_bounds__(256) void transpose_w(const float* __restrict__ in,
                                                   u16* __restrict__ out, int R, int C) {
    __shared__ float t[32][33];
    int tx = threadIdx.x & 31, ty = threadIdx.x >> 5;
    int r0 = blockIdx.y * 32, c0 = blockIdx.x * 32;
#pragma unroll
    for (int i = 0; i < 4; ++i)
        t[ty + 8 * i][tx] = in[(size_t)(r0 + ty + 8 * i) * C + c0 + tx];
    __syncthreads();
#pragma unroll
    for (int i = 0; i < 4; ++i)
        out[(size_t)(c0 + ty + 8 * i) * R + r0 + tx] = f2bf(t[tx][ty + 8 * i]);
}

// ---------------- mod = silu(c) @ Wada + bada   [B,6D] ----------------------------
__global__ __launch_bounds__(256) void modk(const float* __restrict__ c,
                                            const float* __restrict__ Wada,
                                            const float* __restrict__ bada,
                                            float* __restrict__ mod) {
    __shared__ float sc[D_];
    int b = blockIdx.y, tid = threadIdx.x;
    for (int i = tid; i < D_; i += 256) {
        float v = c[b * D_ + i];
        sc[i] = v / (1.f + __expf(-v));
    }
    __syncthreads();
    int col = blockIdx.x * 256 + tid;
    float acc = bada[col];
    for (int k = 0; k < D_; ++k)
        acc = fmaf(sc[k], Wada[(size_t)k * SIXD + col], acc);
    mod[b * SIXD + col] = acc;
}

// ---------------- LN + modulate -> bf16 -------------------------------------------
__global__ __launch_bounds__(256) void ln_mod(const float* __restrict__ x,
                                              const float* __restrict__ mod,
                                              int shift_c, int scale_c,
                                              u16* __restrict__ h) {
    int row = blockIdx.x;           // 0..4095
    int b = row >> 10;
    int tid = threadIdx.x, w = tid >> 6;
    float4 xv = ((const float4*)(x + (size_t)row * D_))[tid];
    float s  = xv.x + xv.y + xv.z + xv.w;
    float s2 = xv.x * xv.x + xv.y * xv.y + xv.z * xv.z + xv.w * xv.w;
#pragma unroll
    for (int m = 1; m <= 32; m <<= 1) { s += __shfl_xor(s, m); s2 += __shfl_xor(s2, m); }
    __shared__ float red[8];
    if ((tid & 63) == 0) { red[w * 2] = s; red[w * 2 + 1] = s2; }
    __syncthreads();
    float S  = red[0] + red[2] + red[4] + red[6];
    float S2 = red[1] + red[3] + red[5] + red[7];
    float mu = S * (1.f / D_);
    float var = S2 * (1.f / D_) - mu * mu;
    float rstd = rsqrtf(var + 1e-6f);
    int d0 = tid * 4;
    float4 shv = *(const float4*)(mod + b * SIXD + shift_c * D_ + d0);
    float4 scv = *(const float4*)(mod + b * SIXD + scale_c * D_ + d0);
    ushort4 o;
    o.x = f2bf((xv.x - mu) * rstd * (1.f + scv.x) + shv.x);
    o.y = f2bf((xv.y - mu) * rstd * (1.f + scv.y) + shv.y);
    o.z = f2bf((xv.z - mu) * rstd * (1.f + scv.z) + shv.z);
    o.w = f2bf((xv.w - mu) * rstd * (1.f + scv.w) + shv.w);
    *(ushort4*)(h + (size_t)row * D_ + d0) = o;
}

// ---------------- generic bf16 GEMM: C = A[M,K] @ Bt[N,K]^T + bias, epilogues -----
// EPI 0: q scatter [B,H,N,DH] bf16
// EPI 1: kv -> k [B,H,N,DH] (out) + v^T [B,H,DH,N] (out2), both bf16
// EPI 2: x1 = xres + mod[gate]*val   (f32 out)
// EPI 3: gelu_tanh(val) -> bf16 out
// EPI 4: out = xres + mod[gate]*val  (f32 out, final)
template <int EPI>
__global__ __launch_bounds__(256) void gemm_bt(const u16* __restrict__ A,
                                               const u16* __restrict__ Bt,
                                               const float* __restrict__ bias,
                                               void* __restrict__ out,
                                               void* __restrict__ out2,
                                               const float* __restrict__ xres,
                                               const float* __restrict__ mod,
                                               int M, int Nn, int K, int gate_c) {
    __shared__ char lds[32768];               // A tile 16KB | B tile 16KB
    const int tid = threadIdx.x;
    const int w = tid >> 6, lane = tid & 63;
    const int li = lane & 15, lg = lane >> 4;
    const int m0 = blockIdx.y * 128, n0 = blockIdx.x * 128;
    const int wr = w >> 1, wc = w & 1;

    f32x4 acc[4][4];
#pragma unroll
    for (int i = 0; i < 4; ++i)
#pragma unroll
        for (int j = 0; j < 4; ++j) acc[i][j] = (f32x4){0.f, 0.f, 0.f, 0.f};

    for (int kk = 0; kk < K; kk += 64) {
#pragma unroll
        for (int j = 0; j < 8; ++j) {
            int idx = j * 256 + w * 64 + lane;     // 0..2047 chunk id
            int idl = idx & 1023;
            int row = idl >> 3, cc = idl & 7;
            const u16* src;
            if (idx < 1024)
                src = A + (size_t)(m0 + row) * K + kk + ((cc ^ (row & 7)) << 3);
            else
                src = Bt + (size_t)(n0 + row) * K + kk + ((cc ^ (row & 7)) << 3);
            gload16(src, lds + (j * 256 + w * 64) * 16);
        }
        __syncthreads();
        const char* Ab = lds;
        const char* Bb = lds + 16384;
#pragma unroll
        for (int hh = 0; hh < 2; ++hh) {
            s16x8 af[4], bfr[4];
#pragma unroll
            for (int mi = 0; mi < 4; ++mi) {
                int r = wr * 64 + mi * 16 + li;
                af[mi] = *(const s16x8*)(Ab + r * 128 + (((hh * 4 + lg) ^ (r & 7)) << 4));
            }
#pragma unroll
            for (int nj = 0; nj < 4; ++nj) {
                int r = wc * 64 + nj * 16 + li;
                bfr[nj] = *(const s16x8*)(Bb + r * 128 + (((hh * 4 + lg) ^ (r & 7)) << 4));
            }
#pragma unroll
            for (int mi = 0; mi < 4; ++mi)
#pragma unroll
                for (int nj = 0; nj < 4; ++nj)
                    acc[mi][nj] = __builtin_amdgcn_mfma_f32_16x16x32_bf16(
                        af[mi], bfr[nj], acc[mi][nj], 0, 0, 0);
        }
        __syncthreads();
    }

    // epilogue
#pragma unroll
    for (int mi = 0; mi < 4; ++mi) {
#pragma unroll
        for (int nj = 0; nj < 4; ++nj) {
            int col = n0 + wc * 64 + nj * 16 + li;
            float bv = bias[col];
#pragma unroll
            for (int rg = 0; rg < 4; ++rg) {
                int grow = m0 + wr * 64 + mi * 16 + 4 * lg + rg;
                float v = acc[mi][nj][rg] + bv;
                int b = grow >> 10, n = grow & 1023;
                if (EPI == 0) {
                    int hd = col >> 6, dh = col & 63;
                    ((u16*)out)[(((size_t)(b * H_ + hd)) * N_ + n) * DH_ + dh] = f2bf(v);
                } else if (EPI == 1) {
                    if (col < D_) {
                        int hd = col >> 6, dh = col & 63;
                        ((u16*)out)[(((size_t)(b * H_ + hd)) * N_ + n) * DH_ + dh] = f2bf(v);
                    } else {
                        int c2 = col - D_;
                        int hd = c2 >> 6, dh = c2 & 63;
                        ((u16*)out2)[(((size_t)(b * H_ + hd)) * DH_ + dh) * N_ + n] = f2bf(v);
                    }
                } else if (EPI == 2 || EPI == 4) {
                    size_t off = (size_t)grow * D_ + col;
                    float g = mod[b * SIXD + gate_c * D_ + col];
                    ((float*)out)[off] = xres[off] + g * v;
                } else if (EPI == 3) {
                    float u = 0.7978845608028654f * v * (1.f + 0.044715f * v * v);
                    u = fminf(fmaxf(u, -15.f), 15.f);
                    float e = __expf(2.f * u);
                    float th = (e - 1.f) / (e + 1.f);
                    ((u16*)out)[(size_t)grow * (size_t)Nn + col] = f2bf(0.5f * v * (1.f + th));
                }
            }
        }
    }
}

// ---------------- flash attention: q,k [B,H,N,DH], vt [B,H,DH,N] -> o [B,N,D] -----
__global__ __launch_bounds__(256) void attn_k(const u16* __restrict__ q,
                                              const u16* __restrict__ k,
                                              const u16* __restrict__ vt,
                                              u16* __restrict__ o) {
    __shared__ char qs[8192], ks[8192], vs[8192];
    __shared__ __align__(16) u16 ps[4][16 * 72];   // per-wave P, stride 72 bf16 = 144B
    const int tid = threadIdx.x, w = tid >> 6, lane = tid & 63;
    const int li = lane & 15, lg = lane >> 4;
    const int qt = blockIdx.x;                 // 16 q-tiles of 64
    const int bh = blockIdx.z * H_ + blockIdx.y;
    const size_t base = (size_t)bh * (N_ * DH_);
    const int q0 = qt * 64;

    // stage Q tile (64x64 bf16, swizzled)
#pragma unroll
    for (int j = 0; j < 2; ++j) {
        int idx = j * 256 + w * 64 + lane;
        int row = idx >> 3, cc = idx & 7;
        gload16(q + base + (size_t)(q0 + row) * DH_ + ((cc ^ (row & 7)) << 3),
                qs + (j * 256 + w * 64) * 16);
    }
    __syncthreads();

    s16x8 qa[2];
    const int qr = w * 16 + li;
#pragma unroll
    for (int hh = 0; hh < 2; ++hh)
        qa[hh] = *(const s16x8*)(qs + qr * 128 + (((hh * 4 + lg) ^ (qr & 7)) << 4));

    f32x4 oac[4];
#pragma unroll
    for (int j = 0; j < 4; ++j) oac[j] = (f32x4){0.f, 0.f, 0.f, 0.f};
    float mrow[4] = {-1e30f, -1e30f, -1e30f, -1e30f};
    float lrow[4] = {0.f, 0.f, 0.f, 0.f};
    const float SC = 0.125f;   // 1/sqrt(DH)

    for (int t = 0; t < 16; ++t) {
        // stage K tile + V^T tile
#pragma unroll
        for (int j = 0; j < 4; ++j) {
            int idx = j * 256 + w * 64 + lane;
            if (j < 2) {
                int row = idx >> 3, cc = idx & 7;
                gload16(k + base + (size_t)(t * 64 + row) * DH_ + ((cc ^ (row & 7)) << 3),
                        ks + (j * 256 + w * 64) * 16);
            } else {
                int idx2 = idx - 512;
                int f = idx2 >> 3, cc = idx2 & 7;
                gload16(vt + base + (size_t)f * N_ + t * 64 + ((cc ^ (f & 7)) << 3),
                        vs + ((j - 2) * 256 + w * 64) * 16);
            }
        }
        __syncthreads();

        // S = Q K^T for this wave's 16 q-rows x 64 keys
        f32x4 sa[4];
#pragma unroll
        for (int kf = 0; kf < 4; ++kf) {
            int kr = kf * 16 + li;
            s16x8 kb0 = *(const s16x8*)(ks + kr * 128 + (((0 + lg) ^ (kr & 7)) << 4));
            s16x8 kb1 = *(const s16x8*)(ks + kr * 128 + (((4 + lg) ^ (kr & 7)) << 4));
            f32x4 z = (f32x4){0.f, 0.f, 0.f, 0.f};
            z = __builtin_amdgcn_mfma_f32_16x16x32_bf16(qa[0], kb0, z, 0, 0, 0);
            z = __builtin_amdgcn_mfma_f32_16x16x32_bf16(qa[1], kb1, z, 0, 0, 0);
            sa[kf] = z;
        }

        // online softmax (rows = 4*lg + rg, cols across 16 lanes of the group)
        float al[4];
#pragma unroll
        for (int rg = 0; rg < 4; ++rg) {
            float v = fmaxf(fmaxf(sa[0][rg], sa[1][rg]), fmaxf(sa[2][rg], sa[3][rg]));
#pragma unroll
            for (int mk = 1; mk <= 8; mk <<= 1) v = fmaxf(v, __shfl_xor(v, mk));
            float mn = fmaxf(mrow[rg], v);
            float a = __expf((mrow[rg] - mn) * SC);
            float rs = 0.f;
#pragma unroll
            for (int kf = 0; kf < 4; ++kf) {
                float p = __expf((sa[kf][rg] - mn) * SC);
                sa[kf][rg] = p;
                rs += p;
            }
#pragma unroll
            for (int mk = 1; mk <= 8; mk <<= 1) rs += __shfl_xor(rs, mk);
            lrow[rg] = lrow[rg] * a + rs;
            mrow[rg] = mn;
            al[rg] = a;
        }
#pragma unroll
        for (int j = 0; j < 4; ++j)
#pragma unroll
            for (int rg = 0; rg < 4; ++rg) oac[j][rg] *= al[rg];

        // P -> LDS (per-wave, padded stride 72)
#pragma unroll
        for (int kf = 0; kf < 4; ++kf)
#pragma unroll
            for (int rg = 0; rg < 4; ++rg)
                ps[w][(4 * lg + rg) * 72 + kf * 16 + li] = f2bf(sa[kf][rg]);

        // O += P @ V
#pragma unroll
        for (int hh = 0; hh < 2; ++hh) {
            s16x8 pa = *(const s16x8*)((const char*)ps[w] + li * 144 + hh * 64 + lg * 16);
#pragma unroll
            for (int fj = 0; fj < 4; ++fj) {
                int vr = fj * 16 + li;
                s16x8 vb = *(const s16x8*)(vs + vr * 128 + (((hh * 4 + lg) ^ (vr & 7)) << 4));
                oac[fj] = __builtin_amdgcn_mfma_f32_16x16x32_bf16(pa, vb, oac[fj], 0, 0, 0);
            }
        }
        __syncthreads();
    }

    // normalize + store to [B,N,D]
    const int b = bh >> 4, hd = bh & 15;
#pragma unroll
    for (int rg = 0; rg < 4; ++rg) {
        float inv = 1.f / lrow[rg];
        int n = q0 + w * 16 + 4 * lg + rg;
#pragma unroll
        for (int fj = 0; fj < 4; ++fj)
            o[(size_t)(b * N_ + n) * D_ + hd * DH_ + fj * 16 + li] = f2bf(oac[fj][rg] * inv);
    }
}

// ---------------------------------------------------------------------------------
extern "C" void kernel_launch(void* const* d_in, const int* in_sizes, int n_in,
                              void* d_out, int out_size, void* d_ws, size_t ws_size,
                              hipStream_t stream) {
    const float* x    = (const float*)d_in[0];
    const float* c    = (const float*)d_in[1];
    const float* Wq   = (const float*)d_in[2];
    const float* bq   = (const float*)d_in[3];
    const float* Wkv  = (const float*)d_in[4];
    const float* bkv  = (const float*)d_in[5];
    const float* Wo   = (const float*)d_in[6];
    const float* bo   = (const float*)d_in[7];
    const float* W1   = (const float*)d_in[8];
    const float* b1   = (const float*)d_in[9];
    const float* W2   = (const float*)d_in[10];
    const float* b2   = (const float*)d_in[11];
    const float* Wada = (const float*)d_in[12];
    const float* bada = (const float*)d_in[13];

    char* ws = (char*)d_ws;
    const size_t MB = 1024 * 1024;
    u16*   wqT  = (u16*)(ws + 0);        // 2MB
    u16*   wkvT = (u16*)(ws + 2 * MB);   // 4MB
    u16*   woT  = (u16*)(ws + 6 * MB);   // 2MB
    u16*   w1T  = (u16*)(ws + 8 * MB);   // 8MB
    u16*   w2T  = (u16*)(ws + 16 * MB);  // 8MB
    float* mod  = (float*)(ws + 24 * MB);// 96KB
    u16*   h    = (u16*)(ws + 25 * MB);  // 8MB (h, later h2)
    u16*   qb   = (u16*)(ws + 33 * MB);  // 8MB
    u16*   kb   = (u16*)(ws + 41 * MB);  // 8MB
    u16*   vtb  = (u16*)(ws + 49 * MB);  // 8MB
    u16*   ao   = (u16*)(ws + 57 * MB);  // 8MB
    float* x1   = (float*)(ws + 65 * MB);// 16MB
    u16*   m1   = (u16*)(ws + 33 * MB);  // 32MB, reuses q/k/vt/ao (dead by then)
    float* outp = (float*)d_out;

    // weights -> bf16, transposed to [out][in]
    transpose_w<<<dim3(32, 32), 256, 0, stream>>>(Wq, wqT, D_, D_);
    transpose_w<<<dim3(64, 32), 256, 0, stream>>>(Wkv, wkvT, D_, 2 * D_);
    transpose_w<<<dim3(32, 32), 256, 0, stream>>>(Wo, woT, D_, D_);
    transpose_w<<<dim3(128, 32), 256, 0, stream>>>(W1, w1T, D_, 4 * D_);
    transpose_w<<<dim3(32, 128), 256, 0, stream>>>(W2, w2T, 4 * D_, D_);

    // adaLN modulation
    modk<<<dim3(24, 4), 256, 0, stream>>>(c, Wada, bada, mod);

    // LN1 + modulate
    ln_mod<<<M_, 256, 0, stream>>>(x, mod, 0, 1, h);

    // q / kv projections
    gemm_bt<0><<<dim3(8, 32), 256, 0, stream>>>(h, wqT, bq, qb, nullptr, nullptr, nullptr,
                                                M_, D_, D_, 0);
    gemm_bt<1><<<dim3(16, 32), 256, 0, stream>>>(h, wkvT, bkv, kb, vtb, nullptr, nullptr,
                                                 M_, 2 * D_, D_, 0);

    // attention
    attn_k<<<dim3(16, H_, B_), 256, 0, stream>>>(qb, kb, vtb, ao);

    // O proj + gated residual -> x1 (f32)
    gemm_bt<2><<<dim3(8, 32), 256, 0, stream>>>(ao, woT, bo, x1, nullptr, x, mod,
                                                M_, D_, D_, 2);

    // LN2 + modulate
    ln_mod<<<M_, 256, 0, stream>>>(x1, mod, 3, 4, h);

    // MLP
    gemm_bt<3><<<dim3(32, 32), 256, 0, stream>>>(h, w1T, b1, m1, nullptr, nullptr, nullptr,
                                                 M_, 4 * D_, D_, 0);
    gemm_bt<4><<<dim3(8, 32), 256, 0, stream>>>(m1, w2T, b2, outp, nullptr, x1, mod,
                                                M_, D_, 4 * D_, 5);
}

// Round 2
// 328.793 us; speedup vs baseline: 1.0486x; 1.0486x over previous
//
#include <hip/hip_runtime.h>
#include <hip/hip_bf16.h>
#include <cstdint>

typedef __attribute__((ext_vector_type(4))) float f32x4;
typedef __attribute__((ext_vector_type(8))) short s16x8;
typedef unsigned short u16;

#define B_  4
#define N_  1024
#define D_  1024
#define H_  16
#define DH_ 64
#define M_  4096      // B_*N_
#define SIXD 6144

__device__ __forceinline__ u16 f2bf(float f) {
    unsigned u = __builtin_bit_cast(unsigned, f);
    unsigned r = (u + 0x7fffu + ((u >> 16) & 1u)) >> 16;
    return (u16)r;
}

__device__ __forceinline__ void gload16(const void* g, void* l) {
    __builtin_amdgcn_global_load_lds((const __attribute__((address_space(1))) void*)g,
                                     (__attribute__((address_space(3))) void*)l,
                                     16, 0, 0);
}

// ---------------- weight convert+transpose: in[R][C] f32 -> out[C][R] bf16 ---------
__global__ __launch_bounds__(256) void transpose_w(const float* __restrict__ in,
                                                   u16* __restrict__ out, int R, int C) {
    __shared__ float t[32][33];
    int tx = threadIdx.x & 31, ty = threadIdx.x >> 5;
    int r0 = blockIdx.y * 32, c0 = blockIdx.x * 32;
#pragma unroll
    for (int i = 0; i < 4; ++i)
        t[ty + 8 * i][tx] = in[(size_t)(r0 + ty + 8 * i) * C + c0 + tx];
    __syncthreads();
#pragma unroll
    for (int i = 0; i < 4; ++i)
        out[(size_t)(c0 + ty + 8 * i) * R + r0 + tx] = f2bf(t[tx][ty + 8 * i]);
}

// ---------------- mod = silu(c) @ Wada + bada   [B,6D] ----------------------------
__global__ __launch_bounds__(256) void modk(const float* __restrict__ c,
                                            const float* __restrict__ Wada,
                                            const float* __restrict__ bada,
                                            float* __restrict__ mod) {
    __shared__ float sc[D_];
    int b = blockIdx.y, tid = threadIdx.x;
    for (int i = tid; i < D_; i += 256) {
        float v = c[b * D_ + i];
        sc[i] = v / (1.f + __expf(-v));
    }
    __syncthreads();
    int col = blockIdx.x * 256 + tid;
    float a0 = 0.f, a1 = 0.f, a2 = 0.f, a3 = 0.f;
    for (int k = 0; k < D_; k += 4) {
        a0 = fmaf(sc[k + 0], Wada[(size_t)(k + 0) * SIXD + col], a0);
        a1 = fmaf(sc[k + 1], Wada[(size_t)(k + 1) * SIXD + col], a1);
        a2 = fmaf(sc[k + 2], Wada[(size_t)(k + 2) * SIXD + col], a2);
        a3 = fmaf(sc[k + 3], Wada[(size_t)(k + 3) * SIXD + col], a3);
    }
    mod[b * SIXD + col] = bada[col] + ((a0 + a1) + (a2 + a3));
}

// ---------------- LN + modulate -> bf16 -------------------------------------------
__global__ __launch_bounds__(256) void ln_mod(const float* __restrict__ x,
                                              const float* __restrict__ mod,
                                              int shift_c, int scale_c,
                                              u16* __restrict__ h) {
    int row = blockIdx.x;           // 0..4095
    int b = row >> 10;
    int tid = threadIdx.x, w = tid >> 6;
    float4 xv = ((const float4*)(x + (size_t)row * D_))[tid];
    float s  = xv.x + xv.y + xv.z + xv.w;
    float s2 = xv.x * xv.x + xv.y * xv.y + xv.z * xv.z + xv.w * xv.w;
#pragma unroll
    for (int m = 1; m <= 32; m <<= 1) { s += __shfl_xor(s, m); s2 += __shfl_xor(s2, m); }
    __shared__ float red[8];
    if ((tid & 63) == 0) { red[w * 2] = s; red[w * 2 + 1] = s2; }
    __syncthreads();
    float S  = red[0] + red[2] + red[4] + red[6];
    float S2 = red[1] + red[3] + red[5] + red[7];
    float mu = S * (1.f / D_);
    float var = S2 * (1.f / D_) - mu * mu;
    float rstd = rsqrtf(var + 1e-6f);
    int d0 = tid * 4;
    float4 shv = *(const float4*)(mod + b * SIXD + shift_c * D_ + d0);
    float4 scv = *(const float4*)(mod + b * SIXD + scale_c * D_ + d0);
    ushort4 o;
    o.x = f2bf((xv.x - mu) * rstd * (1.f + scv.x) + shv.x);
    o.y = f2bf((xv.y - mu) * rstd * (1.f + scv.y) + shv.y);
    o.z = f2bf((xv.z - mu) * rstd * (1.f + scv.z) + shv.z);
    o.w = f2bf((xv.w - mu) * rstd * (1.f + scv.w) + shv.w);
    *(ushort4*)(h + (size_t)row * D_ + d0) = o;
}

// ---------------- generic bf16 GEMM 128x128: C = A @ Bt^T + bias, epilogues -------
// EPI 0: q scatter [B,H,N,DH] bf16
// EPI 1: kv -> k [B,H,N,DH] (out) + v^T [B,H,DH,N] (out2), both bf16
// EPI 2: x1 = xres + mod[gate]*val   (f32 out)
// EPI 3: gelu_tanh(val) -> bf16 out
// EPI 4: out = xres + mod[gate]*val  (f32 out, final)
template <int EPI>
__global__ __launch_bounds__(256) void gemm_bt(const u16* __restrict__ A,
                                               const u16* __restrict__ Bt,
                                               const float* __restrict__ bias,
                                               void* __restrict__ out,
                                               void* __restrict__ out2,
                                               const float* __restrict__ xres,
                                               const float* __restrict__ mod,
                                               int M, int Nn, int K, int gate_c) {
    __shared__ char lds[32768];               // A tile 16KB | B tile 16KB
    const int tid = threadIdx.x;
    const int w = tid >> 6, lane = tid & 63;
    const int li = lane & 15, lg = lane >> 4;
    // XCD-aware chunked swizzle (nwg always a multiple of 8 here)
    const int nwg = gridDim.x * gridDim.y;
    const int flat = blockIdx.y * gridDim.x + blockIdx.x;
    const int wg = (flat & 7) * (nwg >> 3) + (flat >> 3);
    const int m0 = (wg / gridDim.x) * 128, n0 = (wg % gridDim.x) * 128;
    const int wr = w >> 1, wc = w & 1;

    f32x4 acc[4][4];
#pragma unroll
    for (int i = 0; i < 4; ++i)
#pragma unroll
        for (int j = 0; j < 4; ++j) acc[i][j] = (f32x4){0.f, 0.f, 0.f, 0.f};

    for (int kk = 0; kk < K; kk += 64) {
#pragma unroll
        for (int j = 0; j < 8; ++j) {
            int basec = j * 256 + w * 64;          // wave-uniform chunk base
            int idx = basec + lane;                // 0..2047 chunk id
            int idl = idx & 1023;
            int row = idl >> 3, cc = idl & 7;
            const u16* src;
            if (idx < 1024)
                src = A + (size_t)(m0 + row) * K + kk + ((cc ^ (row & 7)) << 3);
            else
                src = Bt + (size_t)(n0 + row) * K + kk + ((cc ^ (row & 7)) << 3);
            gload16(src, lds + basec * 16);
        }
        __syncthreads();
        const char* Ab = lds;
        const char* Bb = lds + 16384;
#pragma unroll
        for (int hh = 0; hh < 2; ++hh) {
            s16x8 af[4], bfr[4];
#pragma unroll
            for (int mi = 0; mi < 4; ++mi) {
                int r = wr * 64 + mi * 16 + li;
                af[mi] = *(const s16x8*)(Ab + r * 128 + (((hh * 4 + lg) ^ (r & 7)) << 4));
            }
#pragma unroll
            for (int nj = 0; nj < 4; ++nj) {
                int r = wc * 64 + nj * 16 + li;
                bfr[nj] = *(const s16x8*)(Bb + r * 128 + (((hh * 4 + lg) ^ (r & 7)) << 4));
            }
#pragma unroll
            for (int mi = 0; mi < 4; ++mi)
#pragma unroll
                for (int nj = 0; nj < 4; ++nj)
                    acc[mi][nj] = __builtin_amdgcn_mfma_f32_16x16x32_bf16(
                        af[mi], bfr[nj], acc[mi][nj], 0, 0, 0);
        }
        __syncthreads();
    }

    // epilogue
#pragma unroll
    for (int mi = 0; mi < 4; ++mi) {
#pragma unroll
        for (int nj = 0; nj < 4; ++nj) {
            int col = n0 + wc * 64 + nj * 16 + li;
            float bv = bias[col];
#pragma unroll
            for (int rg = 0; rg < 4; ++rg) {
                int grow = m0 + wr * 64 + mi * 16 + 4 * lg + rg;
                float v = acc[mi][nj][rg] + bv;
                int b = grow >> 10, n = grow & 1023;
                if (EPI == 0) {
                    int hd = col >> 6, dh = col & 63;
                    ((u16*)out)[(((size_t)(b * H_ + hd)) * N_ + n) * DH_ + dh] = f2bf(v);
                } else if (EPI == 1) {
                    if (col < D_) {
                        int hd = col >> 6, dh = col & 63;
                        ((u16*)out)[(((size_t)(b * H_ + hd)) * N_ + n) * DH_ + dh] = f2bf(v);
                    } else {
                        int c2 = col - D_;
                        int hd = c2 >> 6, dh = c2 & 63;
                        ((u16*)out2)[(((size_t)(b * H_ + hd)) * DH_ + dh) * N_ + n] = f2bf(v);
                    }
                } else if (EPI == 2 || EPI == 4) {
                    size_t off = (size_t)grow * D_ + col;
                    float g = mod[b * SIXD + gate_c * D_ + col];
                    ((float*)out)[off] = xres[off] + g * v;
                } else if (EPI == 3) {
                    float u = 0.7978845608028654f * v * (1.f + 0.044715f * v * v);
                    u = fminf(fmaxf(u, -15.f), 15.f);
                    float e = __expf(2.f * u);
                    float th = (e - 1.f) / (e + 1.f);
                    ((u16*)out)[(size_t)grow * (size_t)Nn + col] = f2bf(0.5f * v * (1.f + th));
                }
            }
        }
    }
}

// ---------------- 256x256 tile GEMM (8 waves), EPI=gelu -> bf16 -------------------
// For W1: M=4096, Nn=4096, K=1024. Grid: 256 blocks (1D), supertiled swizzle.
__global__ __launch_bounds__(512, 2) void gemm256_gelu(const u16* __restrict__ A,
                                                       const u16* __restrict__ Bt,
                                                       const float* __restrict__ bias,
                                                       u16* __restrict__ out,
                                                       int M, int Nn, int K) {
    __shared__ char lds[65536];               // A 32KB | B 32KB
    const int tid = threadIdx.x;
    const int w = tid >> 6, lane = tid & 63;
    const int li = lane & 15, lg = lane >> 4;
    const int wr = w >> 1, wc = w & 1;        // 4 (M) x 2 (N) waves

    // XCD chunk (32 blocks) = 4m x 8n supertile region
    const int flat = blockIdx.x;              // 256 blocks
    const int wg = (flat & 7) * 32 + (flat >> 3);
    const int mg = wg >> 6, r_ = wg & 63;
    const int mt = mg * 4 + (r_ & 3), nt = r_ >> 2;   // 16 x 16 tiles
    const int m0 = mt * 256, n0 = nt * 256;

    f32x4 acc[4][8];
#pragma unroll
    for (int i = 0; i < 4; ++i)
#pragma unroll
        for (int j = 0; j < 8; ++j) acc[i][j] = (f32x4){0.f, 0.f, 0.f, 0.f};

    for (int kk = 0; kk < K; kk += 64) {
#pragma unroll
        for (int j = 0; j < 4; ++j) {
            int basec = j * 512 + w * 64;          // wave-uniform chunk base
            int idx = basec + lane;                // 0..2047
            int row = idx >> 3, cc = idx & 7;
            gload16(A + (size_t)(m0 + row) * K + kk + ((cc ^ (row & 7)) << 3),
                    lds + basec * 16);
            gload16(Bt + (size_t)(n0 + row) * K + kk + ((cc ^ (row & 7)) << 3),
                    lds + 32768 + basec * 16);
        }
        __syncthreads();
        const char* Ab = lds;
        const char* Bb = lds + 32768;
#pragma unroll
        for (int hh = 0; hh < 2; ++hh) {
            s16x8 af[4], bfr[8];
#pragma unroll
            for (int mi = 0; mi < 4; ++mi) {
                int r = wr * 64 + mi * 16 + li;
                af[mi] = *(const s16x8*)(Ab + r * 128 + (((hh * 4 + lg) ^ (r & 7)) << 4));
            }
#pragma unroll
            for (int nj = 0; nj < 8; ++nj) {
                int r = wc * 128 + nj * 16 + li;
                bfr[nj] = *(const s16x8*)(Bb + r * 128 + (((hh * 4 + lg) ^ (r & 7)) << 4));
            }
#pragma unroll
            for (int mi = 0; mi < 4; ++mi)
#pragma unroll
                for (int nj = 0; nj < 8; ++nj)
                    acc[mi][nj] = __builtin_amdgcn_mfma_f32_16x16x32_bf16(
                        af[mi], bfr[nj], acc[mi][nj], 0, 0, 0);
        }
        __syncthreads();
    }

    // epilogue: bias + tanh-GELU -> bf16 row-major [M][Nn]
#pragma unroll
    for (int nj = 0; nj < 8; ++nj) {
        int col = n0 + wc * 128 + nj * 16 + li;
        float bv = bias[col];
#pragma unroll
        for (int mi = 0; mi < 4; ++mi) {
#pragma unroll
            for (int rg = 0; rg < 4; ++rg) {
                int grow = m0 + wr * 64 + mi * 16 + 4 * lg + rg;
                float v = acc[mi][nj][rg] + bv;
                float u = 0.7978845608028654f * v * (1.f + 0.044715f * v * v);
                u = fminf(fmaxf(u, -15.f), 15.f);
                float e = __expf(2.f * u);
                float th = (e - 1.f) / (e + 1.f);
                out[(size_t)grow * (size_t)Nn + col] = f2bf(0.5f * v * (1.f + th));
            }
        }
    }
}

// ---------------- flash attention: q,k [B,H,N,DH], vt [B,H,DH,N] -> o [B,N,D] -----
__global__ __launch_bounds__(256) void attn_k(const u16* __restrict__ q,
                                              const u16* __restrict__ k,
                                              const u16* __restrict__ vt,
                                              u16* __restrict__ o) {
    __shared__ char qs[8192], ks[8192], vs[8192];
    __shared__ __align__(16) u16 ps[4][16 * 72];   // per-wave P, stride 72 bf16 = 144B
    const int tid = threadIdx.x, w = tid >> 6, lane = tid & 63;
    const int li = lane & 15, lg = lane >> 4;
    // swizzle: keep the 16 q-blocks of each (b,h) on one XCD chunk
    const int flat = (blockIdx.z * H_ + blockIdx.y) * 16 + blockIdx.x;  // 1024
    const int wgs = (flat & 7) * 128 + (flat >> 3);
    const int bh = wgs >> 4, qt = wgs & 15;
    const size_t base = (size_t)bh * (N_ * DH_);
    const int q0 = qt * 64;

    // stage Q tile (64x64 bf16, swizzled)
#pragma unroll
    for (int j = 0; j < 2; ++j) {
        int basec = j * 256 + w * 64;
        int idx = basec + lane;
        int row = idx >> 3, cc = idx & 7;
        gload16(q + base + (size_t)(q0 + row) * DH_ + ((cc ^ (row & 7)) << 3),
                qs + basec * 16);
    }
    __syncthreads();

    s16x8 qa[2];
    const int qr = w * 16 + li;
#pragma unroll
    for (int hh = 0; hh < 2; ++hh)
        qa[hh] = *(const s16x8*)(qs + qr * 128 + (((hh * 4 + lg) ^ (qr & 7)) << 4));

    f32x4 oac[4];
#pragma unroll
    for (int j = 0; j < 4; ++j) oac[j] = (f32x4){0.f, 0.f, 0.f, 0.f};
    float mrow[4] = {-1e30f, -1e30f, -1e30f, -1e30f};
    float lrow[4] = {0.f, 0.f, 0.f, 0.f};
    const float SC = 0.125f;   // 1/sqrt(DH)

    for (int t = 0; t < 16; ++t) {
        // stage K tile + V^T tile
#pragma unroll
        for (int j = 0; j < 4; ++j) {
            int basec = j * 256 + w * 64;
            int idx = basec + lane;
            if (j < 2) {
                int row = idx >> 3, cc = idx & 7;
                gload16(k + base + (size_t)(t * 64 + row) * DH_ + ((cc ^ (row & 7)) << 3),
                        ks + basec * 16);
            } else {
                int idx2 = idx - 512;
                int f = idx2 >> 3, cc = idx2 & 7;
                gload16(vt + base + (size_t)f * N_ + t * 64 + ((cc ^ (f & 7)) << 3),
                        vs + (basec - 512) * 16);
            }
        }
        __syncthreads();

        // S = Q K^T for this wave's 16 q-rows x 64 keys
        f32x4 sa[4];
#pragma unroll
        for (int kf = 0; kf < 4; ++kf) {
            int kr = kf * 16 + li;
            s16x8 kb0 = *(const s16x8*)(ks + kr * 128 + (((0 + lg) ^ (kr & 7)) << 4));
            s16x8 kb1 = *(const s16x8*)(ks + kr * 128 + (((4 + lg) ^ (kr & 7)) << 4));
            f32x4 z = (f32x4){0.f, 0.f, 0.f, 0.f};
            z = __builtin_amdgcn_mfma_f32_16x16x32_bf16(qa[0], kb0, z, 0, 0, 0);
            z = __builtin_amdgcn_mfma_f32_16x16x32_bf16(qa[1], kb1, z, 0, 0, 0);
            sa[kf] = z;
        }

        // online softmax (rows = 4*lg + rg, cols across 16 lanes of the group)
        float al[4];
#pragma unroll
        for (int rg = 0; rg < 4; ++rg) {
            float v = fmaxf(fmaxf(sa[0][rg], sa[1][rg]), fmaxf(sa[2][rg], sa[3][rg]));
#pragma unroll
            for (int mk = 1; mk <= 8; mk <<= 1) v = fmaxf(v, __shfl_xor(v, mk));
            float mn = fmaxf(mrow[rg], v);
            float a = __expf((mrow[rg] - mn) * SC);
            float rs = 0.f;
#pragma unroll
            for (int kf = 0; kf < 4; ++kf) {
                float p = __expf((sa[kf][rg] - mn) * SC);
                sa[kf][rg] = p;
                rs += p;
            }
#pragma unroll
            for (int mk = 1; mk <= 8; mk <<= 1) rs += __shfl_xor(rs, mk);
            lrow[rg] = lrow[rg] * a + rs;
            mrow[rg] = mn;
            al[rg] = a;
        }
#pragma unroll
        for (int j = 0; j < 4; ++j)
#pragma unroll
            for (int rg = 0; rg < 4; ++rg) oac[j][rg] *= al[rg];

        // P -> LDS (per-wave, padded stride 72)
#pragma unroll
        for (int kf = 0; kf < 4; ++kf)
#pragma unroll
            for (int rg = 0; rg < 4; ++rg)
                ps[w][(4 * lg + rg) * 72 + kf * 16 + li] = f2bf(sa[kf][rg]);

        // O += P @ V
#pragma unroll
        for (int hh = 0; hh < 2; ++hh) {
            s16x8 pa = *(const s16x8*)((const char*)ps[w] + li * 144 + hh * 64 + lg * 16);
#pragma unroll
            for (int fj = 0; fj < 4; ++fj) {
                int vr = fj * 16 + li;
                s16x8 vb = *(const s16x8*)(vs + vr * 128 + (((hh * 4 + lg) ^ (vr & 7)) << 4));
                oac[fj] = __builtin_amdgcn_mfma_f32_16x16x32_bf16(pa, vb, oac[fj], 0, 0, 0);
            }
        }
        __syncthreads();
    }

    // normalize + store to [B,N,D]
    const int b = bh >> 4, hd = bh & 15;
#pragma unroll
    for (int rg = 0; rg < 4; ++rg) {
        float inv = 1.f / lrow[rg];
        int n = q0 + w * 16 + 4 * lg + rg;
#pragma unroll
        for (int fj = 0; fj < 4; ++fj)
            o[(size_t)(b * N_ + n) * D_ + hd * DH_ + fj * 16 + li] = f2bf(oac[fj][rg] * inv);
    }
}

// ---------------------------------------------------------------------------------
extern "C" void kernel_launch(void* const* d_in, const int* in_sizes, int n_in,
                              void* d_out, int out_size, void* d_ws, size_t ws_size,
                              hipStream_t stream) {
    const float* x    = (const float*)d_in[0];
    const float* c    = (const float*)d_in[1];
    const float* Wq   = (const float*)d_in[2];
    const float* bq   = (const float*)d_in[3];
    const float* Wkv  = (const float*)d_in[4];
    const float* bkv  = (const float*)d_in[5];
    const float* Wo   = (const float*)d_in[6];
    const float* bo   = (const float*)d_in[7];
    const float* W1   = (const float*)d_in[8];
    const float* b1   = (const float*)d_in[9];
    const float* W2   = (const float*)d_in[10];
    const float* b2   = (const float*)d_in[11];
    const float* Wada = (const float*)d_in[12];
    const float* bada = (const float*)d_in[13];

    char* ws = (char*)d_ws;
    const size_t MB = 1024 * 1024;
    u16*   wqT  = (u16*)(ws + 0);        // 2MB
    u16*   wkvT = (u16*)(ws + 2 * MB);   // 4MB
    u16*   woT  = (u16*)(ws + 6 * MB);   // 2MB
    u16*   w1T  = (u16*)(ws + 8 * MB);   // 8MB
    u16*   w2T  = (u16*)(ws + 16 * MB);  // 8MB
    float* mod  = (float*)(ws + 24 * MB);// 96KB
    u16*   h    = (u16*)(ws + 25 * MB);  // 8MB (h, later h2)
    u16*   qb   = (u16*)(ws + 33 * MB);  // 8MB
    u16*   kb   = (u16*)(ws + 41 * MB);  // 8MB
    u16*   vtb  = (u16*)(ws + 49 * MB);  // 8MB
    u16*   ao   = (u16*)(ws + 57 * MB);  // 8MB
    float* x1   = (float*)(ws + 65 * MB);// 16MB
    u16*   m1   = (u16*)(ws + 33 * MB);  // 32MB, reuses q/k/vt/ao (dead by then)
    float* outp = (float*)d_out;

    // weights -> bf16, transposed to [out][in]
    transpose_w<<<dim3(32, 32), 256, 0, stream>>>(Wq, wqT, D_, D_);
    transpose_w<<<dim3(64, 32), 256, 0, stream>>>(Wkv, wkvT, D_, 2 * D_);
    transpose_w<<<dim3(32, 32), 256, 0, stream>>>(Wo, woT, D_, D_);
    transpose_w<<<dim3(128, 32), 256, 0, stream>>>(W1, w1T, D_, 4 * D_);
    transpose_w<<<dim3(32, 128), 256, 0, stream>>>(W2, w2T, 4 * D_, D_);

    // adaLN modulation
    modk<<<dim3(24, 4), 256, 0, stream>>>(c, Wada, bada, mod);

    // LN1 + modulate
    ln_mod<<<M_, 256, 0, stream>>>(x, mod, 0, 1, h);

    // q / kv projections
    gemm_bt<0><<<dim3(8, 32), 256, 0, stream>>>(h, wqT, bq, qb, nullptr, nullptr, nullptr,
                                                M_, D_, D_, 0);
    gemm_bt<1><<<dim3(16, 32), 256, 0, stream>>>(h, wkvT, bkv, kb, vtb, nullptr, nullptr,
                                                 M_, 2 * D_, D_, 0);

    // attention
    attn_k<<<dim3(16, H_, B_), 256, 0, stream>>>(qb, kb, vtb, ao);

    // O proj + gated residual -> x1 (f32)
    gemm_bt<2><<<dim3(8, 32), 256, 0, stream>>>(ao, woT, bo, x1, nullptr, x, mod,
                                                M_, D_, D_, 2);

    // LN2 + modulate
    ln_mod<<<M_, 256, 0, stream>>>(x1, mod, 3, 4, h);

    // MLP
    gemm256_gelu<<<256, 512, 0, stream>>>(h, w1T, b1, m1, M_, 4 * D_, D_);
    gemm_bt<4><<<dim3(8, 32), 256, 0, stream>>>(m1, w2T, b2, outp, nullptr, x1, mod,
                                                M_, D_, 4 * D_, 5);
}

// Round 3
// 284.477 us; speedup vs baseline: 1.2119x; 1.1558x over previous
//
#include <hip/hip_runtime.h>
#include <hip/hip_bf16.h>
#include <cstdint>

typedef __attribute__((ext_vector_type(4))) float f32x4;
typedef __attribute__((ext_vector_type(8))) short s16x8;
typedef unsigned short u16;

#define B_  4
#define N_  1024
#define D_  1024
#define H_  16
#define DH_ 64
#define M_  4096      // B_*N_
#define SIXD 6144

__device__ __forceinline__ u16 f2bf(float f) {
    unsigned u = __builtin_bit_cast(unsigned, f);
    unsigned r = (u + 0x7fffu + ((u >> 16) & 1u)) >> 16;
    return (u16)r;
}

__device__ __forceinline__ void gload16(const void* g, void* l) {
    __builtin_amdgcn_global_load_lds((const __attribute__((address_space(1))) void*)g,
                                     (__attribute__((address_space(3))) void*)l,
                                     16, 0, 0);
}

// ---------------- weight convert+transpose: in[R][C] f32 -> out[C][R] bf16 ---------
__global__ __launch_bounds__(256) void transpose_w(const float* __restrict__ in,
                                                   u16* __restrict__ out, int R, int C) {
    __shared__ float t[32][33];
    int tx = threadIdx.x & 31, ty = threadIdx.x >> 5;
    int r0 = blockIdx.y * 32, c0 = blockIdx.x * 32;
#pragma unroll
    for (int i = 0; i < 4; ++i)
        t[ty + 8 * i][tx] = in[(size_t)(r0 + ty + 8 * i) * C + c0 + tx];
    __syncthreads();
#pragma unroll
    for (int i = 0; i < 4; ++i)
        out[(size_t)(c0 + ty + 8 * i) * R + r0 + tx] = f2bf(t[tx][ty + 8 * i]);
}

// ---------------- mod = silu(c) @ Wada + bada   [B,6D] ----------------------------
__global__ __launch_bounds__(256) void modk(const float* __restrict__ c,
                                            const float* __restrict__ Wada,
                                            const float* __restrict__ bada,
                                            float* __restrict__ mod) {
    __shared__ float sc[D_];
    int b = blockIdx.y, tid = threadIdx.x;
    for (int i = tid; i < D_; i += 256) {
        float v = c[b * D_ + i];
        sc[i] = v / (1.f + __expf(-v));
    }
    __syncthreads();
    int col = blockIdx.x * 256 + tid;
    float a0 = 0.f, a1 = 0.f, a2 = 0.f, a3 = 0.f;
    for (int k = 0; k < D_; k += 4) {
        a0 = fmaf(sc[k + 0], Wada[(size_t)(k + 0) * SIXD + col], a0);
        a1 = fmaf(sc[k + 1], Wada[(size_t)(k + 1) * SIXD + col], a1);
        a2 = fmaf(sc[k + 2], Wada[(size_t)(k + 2) * SIXD + col], a2);
        a3 = fmaf(sc[k + 3], Wada[(size_t)(k + 3) * SIXD + col], a3);
    }
    mod[b * SIXD + col] = bada[col] + ((a0 + a1) + (a2 + a3));
}

// ---------------- LN + modulate -> bf16 -------------------------------------------
__global__ __launch_bounds__(256) void ln_mod(const float* __restrict__ x,
                                              const float* __restrict__ mod,
                                              int shift_c, int scale_c,
                                              u16* __restrict__ h) {
    int row = blockIdx.x;           // 0..4095
    int b = row >> 10;
    int tid = threadIdx.x, w = tid >> 6;
    float4 xv = ((const float4*)(x + (size_t)row * D_))[tid];
    float s  = xv.x + xv.y + xv.z + xv.w;
    float s2 = xv.x * xv.x + xv.y * xv.y + xv.z * xv.z + xv.w * xv.w;
#pragma unroll
    for (int m = 1; m <= 32; m <<= 1) { s += __shfl_xor(s, m); s2 += __shfl_xor(s2, m); }
    __shared__ float red[8];
    if ((tid & 63) == 0) { red[w * 2] = s; red[w * 2 + 1] = s2; }
    __syncthreads();
    float S  = red[0] + red[2] + red[4] + red[6];
    float S2 = red[1] + red[3] + red[5] + red[7];
    float mu = S * (1.f / D_);
    float var = S2 * (1.f / D_) - mu * mu;
    float rstd = rsqrtf(var + 1e-6f);
    int d0 = tid * 4;
    float4 shv = *(const float4*)(mod + b * SIXD + shift_c * D_ + d0);
    float4 scv = *(const float4*)(mod + b * SIXD + scale_c * D_ + d0);
    ushort4 o;
    o.x = f2bf((xv.x - mu) * rstd * (1.f + scv.x) + shv.x);
    o.y = f2bf((xv.y - mu) * rstd * (1.f + scv.y) + shv.y);
    o.z = f2bf((xv.z - mu) * rstd * (1.f + scv.z) + shv.z);
    o.w = f2bf((xv.w - mu) * rstd * (1.f + scv.w) + shv.w);
    *(ushort4*)(h + (size_t)row * D_ + d0) = o;
}

// ---------------- 2-phase double-buffered 128x128 bf16 GEMM -----------------------
// EPI 5: fused qkv scatter: col<1024 -> q [B,H,N,DH]; <2048 -> k (out+4M);
//        else v^T (out+8M, [B,H,DH,N]); bias = bq for q-cols, bias2 = bkv for rest
// EPI 2: x1 = xres + mod[gate]*val   (f32 out)
// EPI 4: out = xres + mod[gate]*val  (f32 out, final)
template <int EPI>
__global__ __launch_bounds__(256) void gemm_bt(const u16* __restrict__ A,
                                               const u16* __restrict__ Bt,
                                               const float* __restrict__ bias,
                                               const float* __restrict__ bias2,
                                               void* __restrict__ out,
                                               const float* __restrict__ xres,
                                               const float* __restrict__ mod,
                                               int M, int Nn, int K, int gate_c) {
    __shared__ char lds[2][32768];            // per buf: A tile 16KB | B tile 16KB
    const int tid = threadIdx.x;
    const int w = tid >> 6, lane = tid & 63;
    const int li = lane & 15, lg = lane >> 4;
    // XCD-aware chunked swizzle (nwg always a multiple of 8 here)
    const int nwg = gridDim.x * gridDim.y;
    const int flat = blockIdx.y * gridDim.x + blockIdx.x;
    const int wg = (flat & 7) * (nwg >> 3) + (flat >> 3);
    const int m0 = (wg / gridDim.x) * 128, n0 = (wg % gridDim.x) * 128;
    const int wr = w >> 1, wc = w & 1;

    f32x4 acc[4][4];
#pragma unroll
    for (int i = 0; i < 4; ++i)
#pragma unroll
        for (int j = 0; j < 4; ++j) acc[i][j] = (f32x4){0.f, 0.f, 0.f, 0.f};

    auto STAGE = [&](int kk, char* buf) {
#pragma unroll
        for (int j = 0; j < 8; ++j) {
            int basec = j * 256 + w * 64;          // wave-uniform chunk base
            int idx = basec + lane;                // 0..2047 chunk id
            int idl = idx & 1023;
            int row = idl >> 3, cc = idl & 7;
            const u16* src;
            if (idx < 1024)
                src = A + (size_t)(m0 + row) * K + kk + ((cc ^ (row & 7)) << 3);
            else
                src = Bt + (size_t)(n0 + row) * K + kk + ((cc ^ (row & 7)) << 3);
            gload16(src, buf + basec * 16);
        }
    };

    const int nt = K >> 6;
    STAGE(0, lds[0]);
    __syncthreads();
    int cur = 0;
    for (int t = 0; t < nt; ++t) {
        if (t + 1 < nt) STAGE((t + 1) << 6, lds[cur ^ 1]);   // prefetch next tile
        const char* Ab = lds[cur];
        const char* Bb = lds[cur] + 16384;
#pragma unroll
        for (int hh = 0; hh < 2; ++hh) {
            s16x8 af[4], bfr[4];
#pragma unroll
            for (int mi = 0; mi < 4; ++mi) {
                int r = wr * 64 + mi * 16 + li;
                af[mi] = *(const s16x8*)(Ab + r * 128 + (((hh * 4 + lg) ^ (r & 7)) << 4));
            }
#pragma unroll
            for (int nj = 0; nj < 4; ++nj) {
                int r = wc * 64 + nj * 16 + li;
                bfr[nj] = *(const s16x8*)(Bb + r * 128 + (((hh * 4 + lg) ^ (r & 7)) << 4));
            }
#pragma unroll
            for (int mi = 0; mi < 4; ++mi)
#pragma unroll
                for (int nj = 0; nj < 4; ++nj)
                    acc[mi][nj] = __builtin_amdgcn_mfma_f32_16x16x32_bf16(
                        af[mi], bfr[nj], acc[mi][nj], 0, 0, 0);
        }
        __syncthreads();   // drains prefetch vmcnt AFTER compute overlapped
        cur ^= 1;
    }

    // epilogue
#pragma unroll
    for (int mi = 0; mi < 4; ++mi) {
#pragma unroll
        for (int nj = 0; nj < 4; ++nj) {
            int col = n0 + wc * 64 + nj * 16 + li;
            float bv;
            if (EPI == 5) bv = (col < D_) ? bias[col] : bias2[col - D_];
            else bv = bias[col];
#pragma unroll
            for (int rg = 0; rg < 4; ++rg) {
                int grow = m0 + wr * 64 + mi * 16 + 4 * lg + rg;
                float v = acc[mi][nj][rg] + bv;
                int b = grow >> 10, n = grow & 1023;
                if (EPI == 5) {
                    if (col < D_) {
                        int hd = col >> 6, dh = col & 63;
                        ((u16*)out)[(((size_t)(b * H_ + hd)) * N_ + n) * DH_ + dh] = f2bf(v);
                    } else if (col < 2 * D_) {
                        int c2 = col - D_;
                        int hd = c2 >> 6, dh = c2 & 63;
                        ((u16*)out)[4194304u + (((size_t)(b * H_ + hd)) * N_ + n) * DH_ + dh] =
                            f2bf(v);
                    } else {
                        int c2 = col - 2 * D_;
                        int hd = c2 >> 6, dh = c2 & 63;
                        ((u16*)out)[8388608u + (((size_t)(b * H_ + hd)) * DH_ + dh) * N_ + n] =
                            f2bf(v);
                    }
                } else if (EPI == 2 || EPI == 4) {
                    size_t off = (size_t)grow * D_ + col;
                    float g = mod[b * SIXD + gate_c * D_ + col];
                    ((float*)out)[off] = xres[off] + g * v;
                }
            }
        }
    }
}

// ---------------- 256x256 tile GEMM (8 waves), 2-phase dbuf, gelu -> bf16 ---------
// For W1: M=4096, Nn=4096, K=1024. Grid: 256 blocks (1D), supertiled swizzle.
__global__ __launch_bounds__(512, 2) void gemm256_gelu(const u16* __restrict__ A,
                                                       const u16* __restrict__ Bt,
                                                       const float* __restrict__ bias,
                                                       u16* __restrict__ out,
                                                       int M, int Nn, int K) {
    __shared__ char lds[2][65536];            // per buf: A 32KB | B 32KB
    const int tid = threadIdx.x;
    const int w = tid >> 6, lane = tid & 63;
    const int li = lane & 15, lg = lane >> 4;
    const int wr = w >> 1, wc = w & 1;        // 4 (M) x 2 (N) waves

    // XCD chunk (32 blocks) = 4m x 8n supertile region
    const int flat = blockIdx.x;              // 256 blocks
    const int wg = (flat & 7) * 32 + (flat >> 3);
    const int mg = wg >> 6, r_ = wg & 63;
    const int mt = mg * 4 + (r_ & 3), nt_ = r_ >> 2;   // 16 x 16 tiles
    const int m0 = mt * 256, n0 = nt_ * 256;

    f32x4 acc[4][8];
#pragma unroll
    for (int i = 0; i < 4; ++i)
#pragma unroll
        for (int j = 0; j < 8; ++j) acc[i][j] = (f32x4){0.f, 0.f, 0.f, 0.f};

    auto STAGE = [&](int kk, char* buf) {
#pragma unroll
        for (int j = 0; j < 4; ++j) {
            int basec = j * 512 + w * 64;          // wave-uniform chunk base
            int idx = basec + lane;                // 0..2047
            int row = idx >> 3, cc = idx & 7;
            gload16(A + (size_t)(m0 + row) * K + kk + ((cc ^ (row & 7)) << 3),
                    buf + basec * 16);
            gload16(Bt + (size_t)(n0 + row) * K + kk + ((cc ^ (row & 7)) << 3),
                    buf + 32768 + basec * 16);
        }
    };

    const int nt = K >> 6;
    STAGE(0, lds[0]);
    __syncthreads();
    int cur = 0;
    for (int t = 0; t < nt; ++t) {
        if (t + 1 < nt) STAGE((t + 1) << 6, lds[cur ^ 1]);
        const char* Ab = lds[cur];
        const char* Bb = lds[cur] + 32768;
#pragma unroll
        for (int hh = 0; hh < 2; ++hh) {
            s16x8 af[4], bfr[8];
#pragma unroll
            for (int mi = 0; mi < 4; ++mi) {
                int r = wr * 64 + mi * 16 + li;
                af[mi] = *(const s16x8*)(Ab + r * 128 + (((hh * 4 + lg) ^ (r & 7)) << 4));
            }
#pragma unroll
            for (int nj = 0; nj < 8; ++nj) {
                int r = wc * 128 + nj * 16 + li;
                bfr[nj] = *(const s16x8*)(Bb + r * 128 + (((hh * 4 + lg) ^ (r & 7)) << 4));
            }
#pragma unroll
            for (int mi = 0; mi < 4; ++mi)
#pragma unroll
                for (int nj = 0; nj < 8; ++nj)
                    acc[mi][nj] = __builtin_amdgcn_mfma_f32_16x16x32_bf16(
                        af[mi], bfr[nj], acc[mi][nj], 0, 0, 0);
        }
        __syncthreads();
        cur ^= 1;
    }

    // epilogue: bias + tanh-GELU -> bf16 row-major [M][Nn]
#pragma unroll
    for (int nj = 0; nj < 8; ++nj) {
        int col = n0 + wc * 128 + nj * 16 + li;
        float bv = bias[col];
#pragma unroll
        for (int mi = 0; mi < 4; ++mi) {
#pragma unroll
            for (int rg = 0; rg < 4; ++rg) {
                int grow = m0 + wr * 64 + mi * 16 + 4 * lg + rg;
                float v = acc[mi][nj][rg] + bv;
                float u = 0.7978845608028654f * v * (1.f + 0.044715f * v * v);
                u = fminf(fmaxf(u, -15.f), 15.f);
                float e = __expf(2.f * u);
                float th = (e - 1.f) / (e + 1.f);
                out[(size_t)grow * (size_t)Nn + col] = f2bf(0.5f * v * (1.f + th));
            }
        }
    }
}

// ---------------- flash attention: q,k [B,H,N,DH], vt [B,H,DH,N] -> o [B,N,D] -----
__global__ __launch_bounds__(256) void attn_k(const u16* __restrict__ q,
                                              const u16* __restrict__ k,
                                              const u16* __restrict__ vt,
                                              u16* __restrict__ o) {
    __shared__ char qs[8192], ks[8192], vs[8192];
    __shared__ __align__(16) u16 ps[4][16 * 72];   // per-wave P, stride 72 bf16 = 144B
    const int tid = threadIdx.x, w = tid >> 6, lane = tid & 63;
    const int li = lane & 15, lg = lane >> 4;
    // swizzle: keep the 16 q-blocks of each (b,h) on one XCD chunk
    const int flat = (blockIdx.z * H_ + blockIdx.y) * 16 + blockIdx.x;  // 1024
    const int wgs = (flat & 7) * 128 + (flat >> 3);
    const int bh = wgs >> 4, qt = wgs & 15;
    const size_t base = (size_t)bh * (N_ * DH_);
    const int q0 = qt * 64;

    // stage Q tile (64x64 bf16, swizzled)
#pragma unroll
    for (int j = 0; j < 2; ++j) {
        int basec = j * 256 + w * 64;
        int idx = basec + lane;
        int row = idx >> 3, cc = idx & 7;
        gload16(q + base + (size_t)(q0 + row) * DH_ + ((cc ^ (row & 7)) << 3),
                qs + basec * 16);
    }
    __syncthreads();

    s16x8 qa[2];
    const int qr = w * 16 + li;
#pragma unroll
    for (int hh = 0; hh < 2; ++hh)
        qa[hh] = *(const s16x8*)(qs + qr * 128 + (((hh * 4 + lg) ^ (qr & 7)) << 4));

    f32x4 oac[4];
#pragma unroll
    for (int j = 0; j < 4; ++j) oac[j] = (f32x4){0.f, 0.f, 0.f, 0.f};
    float mrow[4] = {-1e30f, -1e30f, -1e30f, -1e30f};
    float lrow[4] = {0.f, 0.f, 0.f, 0.f};
    const float SC = 0.125f;   // 1/sqrt(DH)

    for (int t = 0; t < 16; ++t) {
        // stage K tile + V^T tile
#pragma unroll
        for (int j = 0; j < 4; ++j) {
            int basec = j * 256 + w * 64;
            int idx = basec + lane;
            if (j < 2) {
                int row = idx >> 3, cc = idx & 7;
                gload16(k + base + (size_t)(t * 64 + row) * DH_ + ((cc ^ (row & 7)) << 3),
                        ks + basec * 16);
            } else {
                int idx2 = idx - 512;
                int f = idx2 >> 3, cc = idx2 & 7;
                gload16(vt + base + (size_t)f * N_ + t * 64 + ((cc ^ (f & 7)) << 3),
                        vs + (basec - 512) * 16);
            }
        }
        __syncthreads();

        // S = Q K^T for this wave's 16 q-rows x 64 keys
        f32x4 sa[4];
#pragma unroll
        for (int kf = 0; kf < 4; ++kf) {
            int kr = kf * 16 + li;
            s16x8 kb0 = *(const s16x8*)(ks + kr * 128 + (((0 + lg) ^ (kr & 7)) << 4));
            s16x8 kb1 = *(const s16x8*)(ks + kr * 128 + (((4 + lg) ^ (kr & 7)) << 4));
            f32x4 z = (f32x4){0.f, 0.f, 0.f, 0.f};
            z = __builtin_amdgcn_mfma_f32_16x16x32_bf16(qa[0], kb0, z, 0, 0, 0);
            z = __builtin_amdgcn_mfma_f32_16x16x32_bf16(qa[1], kb1, z, 0, 0, 0);
            sa[kf] = z;
        }

        // online softmax (rows = 4*lg + rg, cols across 16 lanes of the group)
        float al[4];
#pragma unroll
        for (int rg = 0; rg < 4; ++rg) {
            float v = fmaxf(fmaxf(sa[0][rg], sa[1][rg]), fmaxf(sa[2][rg], sa[3][rg]));
#pragma unroll
            for (int mk = 1; mk <= 8; mk <<= 1) v = fmaxf(v, __shfl_xor(v, mk));
            float mn = fmaxf(mrow[rg], v);
            float a = __expf((mrow[rg] - mn) * SC);
            float rs = 0.f;
#pragma unroll
            for (int kf = 0; kf < 4; ++kf) {
                float p = __expf((sa[kf][rg] - mn) * SC);
                sa[kf][rg] = p;
                rs += p;
            }
#pragma unroll
            for (int mk = 1; mk <= 8; mk <<= 1) rs += __shfl_xor(rs, mk);
            lrow[rg] = lrow[rg] * a + rs;
            mrow[rg] = mn;
            al[rg] = a;
        }
#pragma unroll
        for (int j = 0; j < 4; ++j)
#pragma unroll
            for (int rg = 0; rg < 4; ++rg) oac[j][rg] *= al[rg];

        // P -> LDS (per-wave, padded stride 72)
#pragma unroll
        for (int kf = 0; kf < 4; ++kf)
#pragma unroll
            for (int rg = 0; rg < 4; ++rg)
                ps[w][(4 * lg + rg) * 72 + kf * 16 + li] = f2bf(sa[kf][rg]);

        // O += P @ V
#pragma unroll
        for (int hh = 0; hh < 2; ++hh) {
            s16x8 pa = *(const s16x8*)((const char*)ps[w] + li * 144 + hh * 64 + lg * 16);
#pragma unroll
            for (int fj = 0; fj < 4; ++fj) {
                int vr = fj * 16 + li;
                s16x8 vb = *(const s16x8*)(vs + vr * 128 + (((hh * 4 + lg) ^ (vr & 7)) << 4));
                oac[fj] = __builtin_amdgcn_mfma_f32_16x16x32_bf16(pa, vb, oac[fj], 0, 0, 0);
            }
        }
        __syncthreads();
    }

    // normalize + store to [B,N,D]
    const int b = bh >> 4, hd = bh & 15;
#pragma unroll
    for (int rg = 0; rg < 4; ++rg) {
        float inv = 1.f / lrow[rg];
        int n = q0 + w * 16 + 4 * lg + rg;
#pragma unroll
        for (int fj = 0; fj < 4; ++fj)
            o[(size_t)(b * N_ + n) * D_ + hd * DH_ + fj * 16 + li] = f2bf(oac[fj][rg] * inv);
    }
}

// ---------------------------------------------------------------------------------
extern "C" void kernel_launch(void* const* d_in, const int* in_sizes, int n_in,
                              void* d_out, int out_size, void* d_ws, size_t ws_size,
                              hipStream_t stream) {
    const float* x    = (const float*)d_in[0];
    const float* c    = (const float*)d_in[1];
    const float* Wq   = (const float*)d_in[2];
    const float* bq   = (const float*)d_in[3];
    const float* Wkv  = (const float*)d_in[4];
    const float* bkv  = (const float*)d_in[5];
    const float* Wo   = (const float*)d_in[6];
    const float* bo   = (const float*)d_in[7];
    const float* W1   = (const float*)d_in[8];
    const float* b1   = (const float*)d_in[9];
    const float* W2   = (const float*)d_in[10];
    const float* b2   = (const float*)d_in[11];
    const float* Wada = (const float*)d_in[12];
    const float* bada = (const float*)d_in[13];

    char* ws = (char*)d_ws;
    const size_t MB = 1024 * 1024;
    u16*   wqkvT = (u16*)(ws + 0);       // 6MB: [3D][D] = Wq^T | Wkv^T
    u16*   woT  = (u16*)(ws + 6 * MB);   // 2MB
    u16*   w1T  = (u16*)(ws + 8 * MB);   // 8MB
    u16*   w2T  = (u16*)(ws + 16 * MB);  // 8MB
    float* mod  = (float*)(ws + 24 * MB);// 96KB
    u16*   h    = (u16*)(ws + 25 * MB);  // 8MB (h, later h2)
    u16*   qb   = (u16*)(ws + 33 * MB);  // 8MB  (qkv base: q | k at +8MB | vt at +16MB)
    u16*   ao   = (u16*)(ws + 57 * MB);  // 8MB
    float* x1   = (float*)(ws + 65 * MB);// 16MB
    u16*   m1   = (u16*)(ws + 33 * MB);  // 32MB, reuses q/k/vt/ao region later? NO - ao at 57 overlaps; m1 = 33..65 includes qkv (dead) and ao?  ao at 57MB is inside 33+32=65 -> ao dead after o-proj, m1 written after. OK.
    float* outp = (float*)d_out;

    // weights -> bf16, transposed to [out][in]; q and kv packed contiguously
    transpose_w<<<dim3(32, 32), 256, 0, stream>>>(Wq, wqkvT, D_, D_);
    transpose_w<<<dim3(64, 32), 256, 0, stream>>>(Wkv, wqkvT + 1024 * 1024, D_, 2 * D_);
    transpose_w<<<dim3(32, 32), 256, 0, stream>>>(Wo, woT, D_, D_);
    transpose_w<<<dim3(128, 32), 256, 0, stream>>>(W1, w1T, D_, 4 * D_);
    transpose_w<<<dim3(32, 128), 256, 0, stream>>>(W2, w2T, 4 * D_, D_);

    // adaLN modulation
    modk<<<dim3(24, 4), 256, 0, stream>>>(c, Wada, bada, mod);

    // LN1 + modulate
    ln_mod<<<M_, 256, 0, stream>>>(x, mod, 0, 1, h);

    // fused qkv projection (N = 3072)
    gemm_bt<5><<<dim3(24, 32), 256, 0, stream>>>(h, wqkvT, bq, bkv, qb, nullptr, nullptr,
                                                 M_, 3 * D_, D_, 0);

    // attention
    attn_k<<<dim3(16, H_, B_), 256, 0, stream>>>(qb, qb + 4194304, qb + 8388608, ao);

    // O proj + gated residual -> x1 (f32)
    gemm_bt<2><<<dim3(8, 32), 256, 0, stream>>>(ao, woT, bo, nullptr, x1, x, mod,
                                                M_, D_, D_, 2);

    // LN2 + modulate
    ln_mod<<<M_, 256, 0, stream>>>(x1, mod, 3, 4, h);

    // MLP
    gemm256_gelu<<<256, 512, 0, stream>>>(h, w1T, b1, m1, M_, 4 * D_, D_);
    gemm_bt<4><<<dim3(8, 32), 256, 0, stream>>>(m1, w2T, b2, nullptr, outp, x1, mod,
                                                M_, D_, 4 * D_, 5);
}

// Round 4
// 261.572 us; speedup vs baseline: 1.3180x; 1.0876x over previous
//
#include <hip/hip_runtime.h>
#include <hip/hip_bf16.h>
#include <cstdint>

typedef __attribute__((ext_vector_type(4))) float f32x4;
typedef __attribute__((ext_vector_type(16))) float f32x16;
typedef __attribute__((ext_vector_type(8))) short s16x8;
typedef __attribute__((ext_vector_type(4))) unsigned u32x4;
typedef unsigned short u16;

#define B_  4
#define N_  1024
#define D_  1024
#define H_  16
#define DH_ 64
#define M_  4096      // B_*N_
#define SIXD 6144

__device__ __forceinline__ u16 f2bf(float f) {
    unsigned u = __builtin_bit_cast(unsigned, f);
    unsigned r = (u + 0x7fffu + ((u >> 16) & 1u)) >> 16;
    return (u16)r;
}

__device__ __forceinline__ unsigned cvtpk(float a, float b) {
    unsigned r;
    asm("v_cvt_pk_bf16_f32 %0, %1, %2" : "=v"(r) : "v"(a), "v"(b));
    return r;
}

__device__ __forceinline__ void gload16(const void* g, void* l) {
    __builtin_amdgcn_global_load_lds((const __attribute__((address_space(1))) void*)g,
                                     (__attribute__((address_space(3))) void*)l,
                                     16, 0, 0);
}

// ---------------- weight convert+transpose: in[R][C] f32 -> out[C][R] bf16 ---------
__global__ __launch_bounds__(256) void transpose_w(const float* __restrict__ in,
                                                   u16* __restrict__ out, int R, int C) {
    __shared__ float t[32][33];
    int tx = threadIdx.x & 31, ty = threadIdx.x >> 5;
    int r0 = blockIdx.y * 32, c0 = blockIdx.x * 32;
#pragma unroll
    for (int i = 0; i < 4; ++i)
        t[ty + 8 * i][tx] = in[(size_t)(r0 + ty + 8 * i) * C + c0 + tx];
    __syncthreads();
#pragma unroll
    for (int i = 0; i < 4; ++i)
        out[(size_t)(c0 + ty + 8 * i) * R + r0 + tx] = f2bf(t[tx][ty + 8 * i]);
}

// ---------------- mod = silu(c) @ Wada + bada   [B,6D] ----------------------------
__global__ __launch_bounds__(256) void modk(const float* __restrict__ c,
                                            const float* __restrict__ Wada,
                                            const float* __restrict__ bada,
                                            float* __restrict__ mod) {
    __shared__ float sc[D_];
    int b = blockIdx.y, tid = threadIdx.x;
    for (int i = tid; i < D_; i += 256) {
        float v = c[b * D_ + i];
        sc[i] = v / (1.f + __expf(-v));
    }
    __syncthreads();
    int col = blockIdx.x * 256 + tid;
    float a0 = 0.f, a1 = 0.f, a2 = 0.f, a3 = 0.f;
    for (int k = 0; k < D_; k += 4) {
        a0 = fmaf(sc[k + 0], Wada[(size_t)(k + 0) * SIXD + col], a0);
        a1 = fmaf(sc[k + 1], Wada[(size_t)(k + 1) * SIXD + col], a1);
        a2 = fmaf(sc[k + 2], Wada[(size_t)(k + 2) * SIXD + col], a2);
        a3 = fmaf(sc[k + 3], Wada[(size_t)(k + 3) * SIXD + col], a3);
    }
    mod[b * SIXD + col] = bada[col] + ((a0 + a1) + (a2 + a3));
}

// ---------------- LN + modulate -> bf16 -------------------------------------------
__global__ __launch_bounds__(256) void ln_mod(const float* __restrict__ x,
                                              const float* __restrict__ mod,
                                              int shift_c, int scale_c,
                                              u16* __restrict__ h) {
    int row = blockIdx.x;           // 0..4095
    int b = row >> 10;
    int tid = threadIdx.x, w = tid >> 6;
    float4 xv = ((const float4*)(x + (size_t)row * D_))[tid];
    float s  = xv.x + xv.y + xv.z + xv.w;
    float s2 = xv.x * xv.x + xv.y * xv.y + xv.z * xv.z + xv.w * xv.w;
#pragma unroll
    for (int m = 1; m <= 32; m <<= 1) { s += __shfl_xor(s, m); s2 += __shfl_xor(s2, m); }
    __shared__ float red[8];
    if ((tid & 63) == 0) { red[w * 2] = s; red[w * 2 + 1] = s2; }
    __syncthreads();
    float S  = red[0] + red[2] + red[4] + red[6];
    float S2 = red[1] + red[3] + red[5] + red[7];
    float mu = S * (1.f / D_);
    float var = S2 * (1.f / D_) - mu * mu;
    float rstd = rsqrtf(var + 1e-6f);
    int d0 = tid * 4;
    float4 shv = *(const float4*)(mod + b * SIXD + shift_c * D_ + d0);
    float4 scv = *(const float4*)(mod + b * SIXD + scale_c * D_ + d0);
    ushort4 o;
    o.x = f2bf((xv.x - mu) * rstd * (1.f + scv.x) + shv.x);
    o.y = f2bf((xv.y - mu) * rstd * (1.f + scv.y) + shv.y);
    o.z = f2bf((xv.z - mu) * rstd * (1.f + scv.z) + shv.z);
    o.w = f2bf((xv.w - mu) * rstd * (1.f + scv.w) + shv.w);
    *(ushort4*)(h + (size_t)row * D_ + d0) = o;
}

// ---------------- 2-phase double-buffered 128x128 bf16 GEMM -----------------------
template <int EPI>
__global__ __launch_bounds__(256) void gemm_bt(const u16* __restrict__ A,
                                               const u16* __restrict__ Bt,
                                               const float* __restrict__ bias,
                                               const float* __restrict__ bias2,
                                               void* __restrict__ out,
                                               const float* __restrict__ xres,
                                               const float* __restrict__ mod,
                                               int M, int Nn, int K, int gate_c) {
    __shared__ char lds[2][32768];            // per buf: A tile 16KB | B tile 16KB
    const int tid = threadIdx.x;
    const int w = tid >> 6, lane = tid & 63;
    const int li = lane & 15, lg = lane >> 4;
    const int nwg = gridDim.x * gridDim.y;
    const int flat = blockIdx.y * gridDim.x + blockIdx.x;
    const int wg = (flat & 7) * (nwg >> 3) + (flat >> 3);
    const int m0 = (wg / gridDim.x) * 128, n0 = (wg % gridDim.x) * 128;
    const int wr = w >> 1, wc = w & 1;

    f32x4 acc[4][4];
#pragma unroll
    for (int i = 0; i < 4; ++i)
#pragma unroll
        for (int j = 0; j < 4; ++j) acc[i][j] = (f32x4){0.f, 0.f, 0.f, 0.f};

    auto STAGE = [&](int kk, char* buf) {
#pragma unroll
        for (int j = 0; j < 8; ++j) {
            int basec = j * 256 + w * 64;
            int idx = basec + lane;
            int idl = idx & 1023;
            int row = idl >> 3, cc = idl & 7;
            const u16* src;
            if (idx < 1024)
                src = A + (size_t)(m0 + row) * K + kk + ((cc ^ (row & 7)) << 3);
            else
                src = Bt + (size_t)(n0 + row) * K + kk + ((cc ^ (row & 7)) << 3);
            gload16(src, buf + basec * 16);
        }
    };

    const int nt = K >> 6;
    STAGE(0, lds[0]);
    __syncthreads();
    int cur = 0;
    for (int t = 0; t < nt; ++t) {
        if (t + 1 < nt) STAGE((t + 1) << 6, lds[cur ^ 1]);
        const char* Ab = lds[cur];
        const char* Bb = lds[cur] + 16384;
#pragma unroll
        for (int hh = 0; hh < 2; ++hh) {
            s16x8 af[4], bfr[4];
#pragma unroll
            for (int mi = 0; mi < 4; ++mi) {
                int r = wr * 64 + mi * 16 + li;
                af[mi] = *(const s16x8*)(Ab + r * 128 + (((hh * 4 + lg) ^ (r & 7)) << 4));
            }
#pragma unroll
            for (int nj = 0; nj < 4; ++nj) {
                int r = wc * 64 + nj * 16 + li;
                bfr[nj] = *(const s16x8*)(Bb + r * 128 + (((hh * 4 + lg) ^ (r & 7)) << 4));
            }
#pragma unroll
            for (int mi = 0; mi < 4; ++mi)
#pragma unroll
                for (int nj = 0; nj < 4; ++nj)
                    acc[mi][nj] = __builtin_amdgcn_mfma_f32_16x16x32_bf16(
                        af[mi], bfr[nj], acc[mi][nj], 0, 0, 0);
        }
        __syncthreads();
        cur ^= 1;
    }

#pragma unroll
    for (int mi = 0; mi < 4; ++mi) {
#pragma unroll
        for (int nj = 0; nj < 4; ++nj) {
            int col = n0 + wc * 64 + nj * 16 + li;
            float bv;
            if (EPI == 5) bv = (col < D_) ? bias[col] : bias2[col - D_];
            else bv = bias[col];
#pragma unroll
            for (int rg = 0; rg < 4; ++rg) {
                int grow = m0 + wr * 64 + mi * 16 + 4 * lg + rg;
                float v = acc[mi][nj][rg] + bv;
                int b = grow >> 10, n = grow & 1023;
                if (EPI == 5) {
                    if (col < D_) {
                        int hd = col >> 6, dh = col & 63;
                        ((u16*)out)[(((size_t)(b * H_ + hd)) * N_ + n) * DH_ + dh] = f2bf(v);
                    } else if (col < 2 * D_) {
                        int c2 = col - D_;
                        int hd = c2 >> 6, dh = c2 & 63;
                        ((u16*)out)[4194304u + (((size_t)(b * H_ + hd)) * N_ + n) * DH_ + dh] =
                            f2bf(v);
                    } else {
                        int c2 = col - 2 * D_;
                        int hd = c2 >> 6, dh = c2 & 63;
                        ((u16*)out)[8388608u + (((size_t)(b * H_ + hd)) * DH_ + dh) * N_ + n] =
                            f2bf(v);
                    }
                } else if (EPI == 2 || EPI == 4) {
                    size_t off = (size_t)grow * D_ + col;
                    float g = mod[b * SIXD + gate_c * D_ + col];
                    ((float*)out)[off] = xres[off] + g * v;
                }
            }
        }
    }
}

// ---------------- 256x256 tile GEMM (8 waves), 2-phase dbuf, gelu -> bf16 ---------
__global__ __launch_bounds__(512, 2) void gemm256_gelu(const u16* __restrict__ A,
                                                       const u16* __restrict__ Bt,
                                                       const float* __restrict__ bias,
                                                       u16* __restrict__ out,
                                                       int M, int Nn, int K) {
    __shared__ char lds[2][65536];            // per buf: A 32KB | B 32KB
    const int tid = threadIdx.x;
    const int w = tid >> 6, lane = tid & 63;
    const int li = lane & 15, lg = lane >> 4;
    const int wr = w >> 1, wc = w & 1;        // 4 (M) x 2 (N) waves

    const int flat = blockIdx.x;              // 256 blocks
    const int wg = (flat & 7) * 32 + (flat >> 3);
    const int mg = wg >> 6, r_ = wg & 63;
    const int mt = mg * 4 + (r_ & 3), nt_ = r_ >> 2;   // 16 x 16 tiles
    const int m0 = mt * 256, n0 = nt_ * 256;

    f32x4 acc[4][8];
#pragma unroll
    for (int i = 0; i < 4; ++i)
#pragma unroll
        for (int j = 0; j < 8; ++j) acc[i][j] = (f32x4){0.f, 0.f, 0.f, 0.f};

    auto STAGE = [&](int kk, char* buf) {
#pragma unroll
        for (int j = 0; j < 4; ++j) {
            int basec = j * 512 + w * 64;
            int idx = basec + lane;
            int row = idx >> 3, cc = idx & 7;
            gload16(A + (size_t)(m0 + row) * K + kk + ((cc ^ (row & 7)) << 3),
                    buf + basec * 16);
            gload16(Bt + (size_t)(n0 + row) * K + kk + ((cc ^ (row & 7)) << 3),
                    buf + 32768 + basec * 16);
        }
    };

    const int nt = K >> 6;
    STAGE(0, lds[0]);
    __syncthreads();
    int cur = 0;
    for (int t = 0; t < nt; ++t) {
        if (t + 1 < nt) STAGE((t + 1) << 6, lds[cur ^ 1]);
        const char* Ab = lds[cur];
        const char* Bb = lds[cur] + 32768;
#pragma unroll
        for (int hh = 0; hh < 2; ++hh) {
            s16x8 af[4], bfr[8];
#pragma unroll
            for (int mi = 0; mi < 4; ++mi) {
                int r = wr * 64 + mi * 16 + li;
                af[mi] = *(const s16x8*)(Ab + r * 128 + (((hh * 4 + lg) ^ (r & 7)) << 4));
            }
#pragma unroll
            for (int nj = 0; nj < 8; ++nj) {
                int r = wc * 128 + nj * 16 + li;
                bfr[nj] = *(const s16x8*)(Bb + r * 128 + (((hh * 4 + lg) ^ (r & 7)) << 4));
            }
#pragma unroll
            for (int mi = 0; mi < 4; ++mi)
#pragma unroll
                for (int nj = 0; nj < 8; ++nj)
                    acc[mi][nj] = __builtin_amdgcn_mfma_f32_16x16x32_bf16(
                        af[mi], bfr[nj], acc[mi][nj], 0, 0, 0);
        }
        __syncthreads();
        cur ^= 1;
    }

#pragma unroll
    for (int nj = 0; nj < 8; ++nj) {
        int col = n0 + wc * 128 + nj * 16 + li;
        float bv = bias[col];
#pragma unroll
        for (int mi = 0; mi < 4; ++mi) {
#pragma unroll
            for (int rg = 0; rg < 4; ++rg) {
                int grow = m0 + wr * 64 + mi * 16 + 4 * lg + rg;
                float v = acc[mi][nj][rg] + bv;
                float u = 0.7978845608028654f * v * (1.f + 0.044715f * v * v);
                u = fminf(fmaxf(u, -15.f), 15.f);
                float e = __expf(2.f * u);
                float th = (e - 1.f) / (e + 1.f);
                out[(size_t)grow * (size_t)Nn + col] = f2bf(0.5f * v * (1.f + th));
            }
        }
    }
}

// ---------------- flash attention v2: 4 warps x 32 q-rows, 32x32 MFMA, swapped ----
// q,k: [B,H,N,DH] bf16; vt: [B,H,DH,N] bf16; o: [B,N,D] bf16
__global__ __launch_bounds__(256) void attn2(const u16* __restrict__ q,
                                             const u16* __restrict__ k,
                                             const u16* __restrict__ vt,
                                             u16* __restrict__ o) {
    __shared__ __align__(16) char qs[16384];       // Q tile [128 q][64 dh], later O
    __shared__ __align__(16) char kv[2][16384];    // K [64 key][64 dh] | VT [64 d][64 key]
    const int tid = threadIdx.x, w = tid >> 6, lane = tid & 63;
    const int l31 = lane & 31, hi = lane >> 5;
    // XCD swizzle: 64 consecutive wgs (8 full bh) per XCD
    const int flat = blockIdx.x;                   // 512
    const int wgs = (flat & 7) * 64 + (flat >> 3);
    const int bh = wgs >> 3, qt = wgs & 7;
    const size_t base = (size_t)bh * (N_ * DH_);
    const int q0 = qt * 128;

    // stage Q [128][64] (swizzled source)
#pragma unroll
    for (int j = 0; j < 4; ++j) {
        int basec = j * 256 + w * 64;
        int idx = basec + lane;
        int row = idx >> 3, cc = idx & 7;
        gload16(q + base + (size_t)(q0 + row) * DH_ + ((cc ^ (row & 7)) << 3),
                qs + basec * 16);
    }
    auto STAGEKV = [&](int t, char* buf) {
#pragma unroll
        for (int j = 0; j < 4; ++j) {
            int basec = j * 256 + w * 64;
            int idx = basec + lane;
            if (idx < 512) {
                int row = idx >> 3, cc = idx & 7;
                gload16(k + base + (size_t)(t * 64 + row) * DH_ + ((cc ^ (row & 7)) << 3),
                        buf + basec * 16);
            } else {
                int i2 = idx - 512;
                int row = i2 >> 3, cc = i2 & 7;
                gload16(vt + base + (size_t)row * N_ + t * 64 + ((cc ^ (row & 7)) << 3),
                        buf + basec * 16);
            }
        }
    };
    STAGEKV(0, kv[0]);
    __syncthreads();

    // Q fragments (B-operand): lane holds Q[q=w*32+l31][dh = st*16 + hi*8 + 0..7]
    s16x8 qf[4];
    const int qr = w * 32 + l31;
#pragma unroll
    for (int st = 0; st < 4; ++st)
        qf[st] = *(const s16x8*)(qs + qr * 128 + (((st * 2 + hi) ^ (qr & 7)) << 4));

    f32x16 oa[2];
#pragma unroll
    for (int r = 0; r < 16; ++r) { oa[0][r] = 0.f; oa[1][r] = 0.f; }
    float mrow = -3e38f, lrow = 0.f;
    const float CSC = 0.125f * 1.44269504088896f;   // scale * log2(e)

    int cur = 0;
    for (int t = 0; t < 16; ++t) {
        if (t + 1 < 16) STAGEKV(t + 1, kv[cur ^ 1]);
        const char* Kb = kv[cur];
        const char* Vb = kv[cur] + 8192;

        // S^T = K @ Q^T : D[key][q], lane: q = l31, keys = subtile pattern
        f32x16 s[2];
#pragma unroll
        for (int r = 0; r < 16; ++r) { s[0][r] = 0.f; s[1][r] = 0.f; }
#pragma unroll
        for (int st = 0; st < 4; ++st) {
#pragma unroll
            for (int ks = 0; ks < 2; ++ks) {
                int r = ks * 32 + l31;
                s16x8 ka = *(const s16x8*)(Kb + r * 128 + (((st * 2 + hi) ^ (r & 7)) << 4));
                s[ks] = __builtin_amdgcn_mfma_f32_32x32x16_bf16(ka, qf[st], s[ks], 0, 0, 0);
            }
        }

        // online softmax: full P-row (32 of 64 keys) in-lane; partner = lane^32
        float tmax = s[0][0];
#pragma unroll
        for (int r = 1; r < 16; ++r) tmax = fmaxf(tmax, s[0][r]);
#pragma unroll
        for (int r = 0; r < 16; ++r) tmax = fmaxf(tmax, s[1][r]);
        tmax = fmaxf(tmax, __shfl_xor(tmax, 32));
        float mn = fmaxf(mrow, tmax);
        float al = __builtin_amdgcn_exp2f((mrow - mn) * CSC);
        float nmc = -mn * CSC;
        float rs0 = 0.f, rs1 = 0.f;
#pragma unroll
        for (int r = 0; r < 16; ++r) {
            float p0 = __builtin_amdgcn_exp2f(fmaf(s[0][r], CSC, nmc));
            float p1 = __builtin_amdgcn_exp2f(fmaf(s[1][r], CSC, nmc));
            s[0][r] = p0; s[1][r] = p1;
            rs0 += p0; rs1 += p1;
        }
        float rs = rs0 + rs1;
        rs += __shfl_xor(rs, 32);
        lrow = lrow * al + rs;
        mrow = mn;
#pragma unroll
        for (int r = 0; r < 16; ++r) { oa[0][r] *= al; oa[1][r] *= al; }

        // pack P -> bf16 pairs along k: u[ks*8+2j+p] covers k = ks*32+8j+4hi+2p..+1
        unsigned u[16];
#pragma unroll
        for (int ks = 0; ks < 2; ++ks)
#pragma unroll
            for (int j = 0; j < 4; ++j) {
                u[ks * 8 + 2 * j]     = cvtpk(s[ks][4 * j + 0], s[ks][4 * j + 1]);
                u[ks * 8 + 2 * j + 1] = cvtpk(s[ks][4 * j + 2], s[ks][4 * j + 3]);
            }

        // O^T += V^T @ P^T : 4 ksteps of 16 keys
#pragma unroll
        for (int kstep = 0; kstep < 4; ++kstep) {
            unsigned b0 = u[kstep * 4 + 0], b1 = u[kstep * 4 + 1];
            unsigned b2 = u[kstep * 4 + 2], b3 = u[kstep * 4 + 3];
            asm volatile("v_permlane32_swap_b32 %0, %1" : "+v"(b0), "+v"(b2));
            asm volatile("v_permlane32_swap_b32 %0, %1" : "+v"(b1), "+v"(b3));
            u32x4 pbu = (u32x4){b0, b1, b2, b3};
            s16x8 pb = __builtin_bit_cast(s16x8, pbu);
#pragma unroll
            for (int ds = 0; ds < 2; ++ds) {
                int r = ds * 32 + l31;
                s16x8 va = *(const s16x8*)(Vb + r * 128 + (((kstep * 2 + hi) ^ (r & 7)) << 4));
                oa[ds] = __builtin_amdgcn_mfma_f32_32x32x16_bf16(va, pb, oa[ds], 0, 0, 0);
            }
        }
        __syncthreads();
        cur ^= 1;
    }

    // epilogue: normalize, transpose via LDS (reuse qs), coalesced store
    float inv = 1.f / lrow;
#pragma unroll
    for (int ds = 0; ds < 2; ++ds)
#pragma unroll
        for (int j = 0; j < 4; ++j)
#pragma unroll
            for (int t2 = 0; t2 < 2; ++t2) {
                unsigned pk = cvtpk(oa[ds][4 * j + 2 * t2] * inv,
                                    oa[ds][4 * j + 2 * t2 + 1] * inv);
                int row = qr;                       // w*32 + l31
                int dch = 4 * ds + j;               // d chunk (8 u16)
                *(unsigned*)(qs + row * 128 + ((dch ^ (row & 7)) << 4) +
                             (4 * hi + 2 * t2) * 2) = pk;
            }
    __syncthreads();
    {
        int r = tid >> 1, h2 = tid & 1;
        const int b = bh >> 4, hd = bh & 15;
        size_t obase = ((size_t)(b * N_ + q0 + r)) * D_ + hd * DH_;
#pragma unroll
        for (int c = 0; c < 4; ++c) {
            int c2 = h2 * 4 + c;
            s16x8 v = *(const s16x8*)(qs + r * 128 + ((c2 ^ (r & 7)) << 4));
            *(s16x8*)(o + obase + c2 * 8) = v;
        }
    }
}

// ---------------------------------------------------------------------------------
extern "C" void kernel_launch(void* const* d_in, const int* in_sizes, int n_in,
                              void* d_out, int out_size, void* d_ws, size_t ws_size,
                              hipStream_t stream) {
    const float* x    = (const float*)d_in[0];
    const float* c    = (const float*)d_in[1];
    const float* Wq   = (const float*)d_in[2];
    const float* bq   = (const float*)d_in[3];
    const float* Wkv  = (const float*)d_in[4];
    const float* bkv  = (const float*)d_in[5];
    const float* Wo   = (const float*)d_in[6];
    const float* bo   = (const float*)d_in[7];
    const float* W1   = (const float*)d_in[8];
    const float* b1   = (const float*)d_in[9];
    const float* W2   = (const float*)d_in[10];
    const float* b2   = (const float*)d_in[11];
    const float* Wada = (const float*)d_in[12];
    const float* bada = (const float*)d_in[13];

    char* ws = (char*)d_ws;
    const size_t MB = 1024 * 1024;
    u16*   wqkvT = (u16*)(ws + 0);       // 6MB: [3D][D] = Wq^T | Wkv^T
    u16*   woT  = (u16*)(ws + 6 * MB);   // 2MB
    u16*   w1T  = (u16*)(ws + 8 * MB);   // 8MB
    u16*   w2T  = (u16*)(ws + 16 * MB);  // 8MB
    float* mod  = (float*)(ws + 24 * MB);// 96KB
    u16*   h    = (u16*)(ws + 25 * MB);  // 8MB (h, later h2)
    u16*   qb   = (u16*)(ws + 33 * MB);  // 24MB: q | k(+8MB) | vt(+16MB)
    u16*   ao   = (u16*)(ws + 57 * MB);  // 8MB
    float* x1   = (float*)(ws + 65 * MB);// 16MB
    u16*   m1   = (u16*)(ws + 33 * MB);  // 32MB, reuses qkv+ao (dead by then)
    float* outp = (float*)d_out;

    transpose_w<<<dim3(32, 32), 256, 0, stream>>>(Wq, wqkvT, D_, D_);
    transpose_w<<<dim3(64, 32), 256, 0, stream>>>(Wkv, wqkvT + 1024 * 1024, D_, 2 * D_);
    transpose_w<<<dim3(32, 32), 256, 0, stream>>>(Wo, woT, D_, D_);
    transpose_w<<<dim3(128, 32), 256, 0, stream>>>(W1, w1T, D_, 4 * D_);
    transpose_w<<<dim3(32, 128), 256, 0, stream>>>(W2, w2T, 4 * D_, D_);

    modk<<<dim3(24, 4), 256, 0, stream>>>(c, Wada, bada, mod);
    ln_mod<<<M_, 256, 0, stream>>>(x, mod, 0, 1, h);

    gemm_bt<5><<<dim3(24, 32), 256, 0, stream>>>(h, wqkvT, bq, bkv, qb, nullptr, nullptr,
                                                 M_, 3 * D_, D_, 0);

    attn2<<<512, 256, 0, stream>>>(qb, qb + 4194304, qb + 8388608, ao);

    gemm_bt<2><<<dim3(8, 32), 256, 0, stream>>>(ao, woT, bo, nullptr, x1, x, mod,
                                                M_, D_, D_, 2);

    ln_mod<<<M_, 256, 0, stream>>>(x1, mod, 3, 4, h);

    gemm256_gelu<<<256, 512, 0, stream>>>(h, w1T, b1, m1, M_, 4 * D_, D_);
    gemm_bt<4><<<dim3(8, 32), 256, 0, stream>>>(m1, w2T, b2, nullptr, outp, x1, mod,
                                                M_, D_, 4 * D_, 5);
}

// Round 5
// 252.353 us; speedup vs baseline: 1.3662x; 1.0365x over previous
//
#include <hip/hip_runtime.h>
#include <hip/hip_bf16.h>
#include <cstdint>

typedef __attribute__((ext_vector_type(4))) float f32x4;
typedef __attribute__((ext_vector_type(16))) float f32x16;
typedef __attribute__((ext_vector_type(8))) short s16x8;
typedef __attribute__((ext_vector_type(4))) unsigned u32x4;
typedef unsigned short u16;

#define B_  4
#define N_  1024
#define D_  1024
#define H_  16
#define DH_ 64
#define M_  4096      // B_*N_
#define SIXD 6144

#define WAITV(n) asm volatile("s_waitcnt vmcnt(" #n ")" ::: "memory")

__device__ __forceinline__ u16 f2bf(float f) {
    unsigned u = __builtin_bit_cast(unsigned, f);
    unsigned r = (u + 0x7fffu + ((u >> 16) & 1u)) >> 16;
    return (u16)r;
}

__device__ __forceinline__ unsigned cvtpk(float a, float b) {
    unsigned r;
    asm("v_cvt_pk_bf16_f32 %0, %1, %2" : "=v"(r) : "v"(a), "v"(b));
    return r;
}

__device__ __forceinline__ void gload16(const void* g, void* l) {
    __builtin_amdgcn_global_load_lds((const __attribute__((address_space(1))) void*)g,
                                     (__attribute__((address_space(3))) void*)l,
                                     16, 0, 0);
}

// ---------------- all weight transposes in ONE launch: in[R][C] f32 -> out[C][R] bf16
__global__ __launch_bounds__(256) void transpose_all(const float* __restrict__ Wq,
                                                     const float* __restrict__ Wkv,
                                                     const float* __restrict__ Wo,
                                                     const float* __restrict__ W1,
                                                     const float* __restrict__ W2,
                                                     u16* __restrict__ wqkvT,
                                                     u16* __restrict__ woT,
                                                     u16* __restrict__ w1T,
                                                     u16* __restrict__ w2T) {
    int id = blockIdx.x;
    const float* in; u16* outp; int R, C, loc;
    if (id < 1024)      { in = Wq;  outp = wqkvT;           R = 1024; C = 1024; loc = id; }
    else if (id < 3072) { in = Wkv; outp = wqkvT + 1048576; R = 1024; C = 2048; loc = id - 1024; }
    else if (id < 4096) { in = Wo;  outp = woT;             R = 1024; C = 1024; loc = id - 3072; }
    else if (id < 8192) { in = W1;  outp = w1T;             R = 1024; C = 4096; loc = id - 4096; }
    else                { in = W2;  outp = w2T;             R = 4096; C = 1024; loc = id - 8192; }
    int tpc = C >> 5;
    int bx = loc % tpc, by = loc / tpc;
    __shared__ float t[32][33];
    int tx = threadIdx.x & 31, ty = threadIdx.x >> 5;
    int r0 = by * 32, c0 = bx * 32;
#pragma unroll
    for (int i = 0; i < 4; ++i)
        t[ty + 8 * i][tx] = in[(size_t)(r0 + ty + 8 * i) * C + c0 + tx];
    __syncthreads();
#pragma unroll
    for (int i = 0; i < 4; ++i)
        outp[(size_t)(c0 + ty + 8 * i) * R + r0 + tx] = f2bf(t[tx][ty + 8 * i]);
}

// ---------------- mod = silu(c) @ Wada + bada   [B,6D] ----------------------------
__global__ __launch_bounds__(256) void modk(const float* __restrict__ c,
                                            const float* __restrict__ Wada,
                                            const float* __restrict__ bada,
                                            float* __restrict__ mod) {
    __shared__ float sc[D_];
    int b = blockIdx.y, tid = threadIdx.x;
    for (int i = tid; i < D_; i += 256) {
        float v = c[b * D_ + i];
        sc[i] = v / (1.f + __expf(-v));
    }
    __syncthreads();
    int col = blockIdx.x * 256 + tid;
    float a0 = 0.f, a1 = 0.f, a2 = 0.f, a3 = 0.f;
    for (int k = 0; k < D_; k += 4) {
        a0 = fmaf(sc[k + 0], Wada[(size_t)(k + 0) * SIXD + col], a0);
        a1 = fmaf(sc[k + 1], Wada[(size_t)(k + 1) * SIXD + col], a1);
        a2 = fmaf(sc[k + 2], Wada[(size_t)(k + 2) * SIXD + col], a2);
        a3 = fmaf(sc[k + 3], Wada[(size_t)(k + 3) * SIXD + col], a3);
    }
    mod[b * SIXD + col] = bada[col] + ((a0 + a1) + (a2 + a3));
}

// ---------------- LN + modulate -> bf16 -------------------------------------------
__global__ __launch_bounds__(256) void ln_mod(const float* __restrict__ x,
                                              const float* __restrict__ mod,
                                              int shift_c, int scale_c,
                                              u16* __restrict__ h) {
    int row = blockIdx.x;           // 0..4095
    int b = row >> 10;
    int tid = threadIdx.x, w = tid >> 6;
    float4 xv = ((const float4*)(x + (size_t)row * D_))[tid];
    float s  = xv.x + xv.y + xv.z + xv.w;
    float s2 = xv.x * xv.x + xv.y * xv.y + xv.z * xv.z + xv.w * xv.w;
#pragma unroll
    for (int m = 1; m <= 32; m <<= 1) { s += __shfl_xor(s, m); s2 += __shfl_xor(s2, m); }
    __shared__ float red[8];
    if ((tid & 63) == 0) { red[w * 2] = s; red[w * 2 + 1] = s2; }
    __syncthreads();
    float S  = red[0] + red[2] + red[4] + red[6];
    float S2 = red[1] + red[3] + red[5] + red[7];
    float mu = S * (1.f / D_);
    float var = S2 * (1.f / D_) - mu * mu;
    float rstd = rsqrtf(var + 1e-6f);
    int d0 = tid * 4;
    float4 shv = *(const float4*)(mod + b * SIXD + shift_c * D_ + d0);
    float4 scv = *(const float4*)(mod + b * SIXD + scale_c * D_ + d0);
    ushort4 o;
    o.x = f2bf((xv.x - mu) * rstd * (1.f + scv.x) + shv.x);
    o.y = f2bf((xv.y - mu) * rstd * (1.f + scv.y) + shv.y);
    o.z = f2bf((xv.z - mu) * rstd * (1.f + scv.z) + shv.z);
    o.w = f2bf((xv.w - mu) * rstd * (1.f + scv.w) + shv.w);
    *(ushort4*)(h + (size_t)row * D_ + d0) = o;
}

// ---------------- counted-vmcnt 2-phase 128x128 bf16 GEMM -------------------------
// EPI 2: x1 = xres + mod[gate]*val   (f32 out)
// EPI 4: out = xres + mod[gate]*val  (f32 out, final)
template <int EPI>
__global__ __launch_bounds__(256) void gemm_bt(const u16* __restrict__ A,
                                               const u16* __restrict__ Bt,
                                               const float* __restrict__ bias,
                                               void* __restrict__ out,
                                               const float* __restrict__ xres,
                                               const float* __restrict__ mod,
                                               int M, int Nn, int K, int gate_c) {
    __shared__ char lds[2][32768];            // per buf: A tile 16KB | B tile 16KB
    const int tid = threadIdx.x;
    const int w = tid >> 6, lane = tid & 63;
    const int li = lane & 15, lg = lane >> 4;
    const int nwg = gridDim.x * gridDim.y;
    const int flat = blockIdx.y * gridDim.x + blockIdx.x;
    const int wg = (flat & 7) * (nwg >> 3) + (flat >> 3);
    const int m0 = (wg / gridDim.x) * 128, n0 = (wg % gridDim.x) * 128;
    const int wr = w >> 1, wc = w & 1;

    f32x4 acc[4][4];
#pragma unroll
    for (int i = 0; i < 4; ++i)
#pragma unroll
        for (int j = 0; j < 4; ++j) acc[i][j] = (f32x4){0.f, 0.f, 0.f, 0.f};

    auto STAGE = [&](int kk, char* buf) {
#pragma unroll
        for (int j = 0; j < 8; ++j) {
            int basec = j * 256 + w * 64;
            int idx = basec + lane;
            int idl = idx & 1023;
            int row = idl >> 3, cc = idl & 7;
            const u16* src;
            if (idx < 1024)
                src = A + (size_t)(m0 + row) * K + kk + ((cc ^ (row & 7)) << 3);
            else
                src = Bt + (size_t)(n0 + row) * K + kk + ((cc ^ (row & 7)) << 3);
            gload16(src, buf + basec * 16);
        }
    };

    const int nt = K >> 6;
    STAGE(0, lds[0]);
    __syncthreads();
    int cur = 0;
    for (int t = 0; t < nt; ++t) {
        if (t + 1 < nt) { STAGE((t + 1) << 6, lds[cur ^ 1]); WAITV(8); }
        else WAITV(0);
        __builtin_amdgcn_s_barrier();
        __builtin_amdgcn_sched_barrier(0);
        const char* Ab = lds[cur];
        const char* Bb = lds[cur] + 16384;
#pragma unroll
        for (int hh = 0; hh < 2; ++hh) {
            s16x8 af[4], bfr[4];
#pragma unroll
            for (int mi = 0; mi < 4; ++mi) {
                int r = wr * 64 + mi * 16 + li;
                af[mi] = *(const s16x8*)(Ab + r * 128 + (((hh * 4 + lg) ^ (r & 7)) << 4));
            }
#pragma unroll
            for (int nj = 0; nj < 4; ++nj) {
                int r = wc * 64 + nj * 16 + li;
                bfr[nj] = *(const s16x8*)(Bb + r * 128 + (((hh * 4 + lg) ^ (r & 7)) << 4));
            }
#pragma unroll
            for (int mi = 0; mi < 4; ++mi)
#pragma unroll
                for (int nj = 0; nj < 4; ++nj)
                    acc[mi][nj] = __builtin_amdgcn_mfma_f32_16x16x32_bf16(
                        af[mi], bfr[nj], acc[mi][nj], 0, 0, 0);
        }
        __builtin_amdgcn_s_barrier();
        cur ^= 1;
    }

#pragma unroll
    for (int mi = 0; mi < 4; ++mi) {
#pragma unroll
        for (int nj = 0; nj < 4; ++nj) {
            int col = n0 + wc * 64 + nj * 16 + li;
            float bv = bias[col];
#pragma unroll
            for (int rg = 0; rg < 4; ++rg) {
                int grow = m0 + wr * 64 + mi * 16 + 4 * lg + rg;
                float v = acc[mi][nj][rg] + bv;
                int b = grow >> 10;
                size_t off = (size_t)grow * D_ + col;
                float g = mod[b * SIXD + gate_c * D_ + col];
                ((float*)out)[off] = xres[off] + g * v;
            }
        }
    }
}

// ---------------- counted-vmcnt 2-phase 256x256 GEMM (8 waves) --------------------
// EPI 3: gelu_tanh(val) -> bf16 out [M][Nn]
// EPI 5: qkv scatter: n0<1024 -> q; <2048 -> k (+4M elems); else v^T (+8M elems)
template <int EPI>
__global__ __launch_bounds__(512, 2) void gemm256(const u16* __restrict__ A,
                                                  const u16* __restrict__ Bt,
                                                  const float* __restrict__ bias,
                                                  const float* __restrict__ bias2,
                                                  void* __restrict__ out,
                                                  int M, int Nn, int K,
                                                  int cm, int cn) {
    __shared__ char lds[2][65536];            // per buf: A 32KB | B 32KB
    const int tid = threadIdx.x;
    const int w = tid >> 6, lane = tid & 63;
    const int li = lane & 15, lg = lane >> 4;
    const int wr = w >> 1, wc = w & 1;        // 4 (M) x 2 (N) waves

    // XCD-chunked bijective swizzle: xcd = flat&7 owns a cm x cn chunk of tiles
    const int flat = blockIdx.x;
    const int xcd = flat & 7, r_ = flat >> 3;
    const int ntn = Nn >> 8;
    const int ncc = ntn / cn;                 // chunk-cols
    const int mt = (xcd / ncc) * cm + (r_ % cm);
    const int nt_ = (xcd % ncc) * cn + (r_ / cm);
    const int m0 = mt * 256, n0 = nt_ * 256;

    f32x4 acc[4][8];
#pragma unroll
    for (int i = 0; i < 4; ++i)
#pragma unroll
        for (int j = 0; j < 8; ++j) acc[i][j] = (f32x4){0.f, 0.f, 0.f, 0.f};

    auto STAGE = [&](int kk, char* buf) {
#pragma unroll
        for (int j = 0; j < 4; ++j) {
            int basec = j * 512 + w * 64;
            int idx = basec + lane;
            int row = idx >> 3, cc = idx & 7;
            gload16(A + (size_t)(m0 + row) * K + kk + ((cc ^ (row & 7)) << 3),
                    buf + basec * 16);
            gload16(Bt + (size_t)(n0 + row) * K + kk + ((cc ^ (row & 7)) << 3),
                    buf + 32768 + basec * 16);
        }
    };

    const int nt = K >> 6;
    STAGE(0, lds[0]);
    __syncthreads();
    int cur = 0;
    for (int t = 0; t < nt; ++t) {
        if (t + 1 < nt) { STAGE((t + 1) << 6, lds[cur ^ 1]); WAITV(8); }
        else WAITV(0);
        __builtin_amdgcn_s_barrier();
        __builtin_amdgcn_sched_barrier(0);
        const char* Ab = lds[cur];
        const char* Bb = lds[cur] + 32768;
#pragma unroll
        for (int hh = 0; hh < 2; ++hh) {
            s16x8 af[4], bfr[8];
#pragma unroll
            for (int mi = 0; mi < 4; ++mi) {
                int r = wr * 64 + mi * 16 + li;
                af[mi] = *(const s16x8*)(Ab + r * 128 + (((hh * 4 + lg) ^ (r & 7)) << 4));
            }
#pragma unroll
            for (int nj = 0; nj < 8; ++nj) {
                int r = wc * 128 + nj * 16 + li;
                bfr[nj] = *(const s16x8*)(Bb + r * 128 + (((hh * 4 + lg) ^ (r & 7)) << 4));
            }
#pragma unroll
            for (int mi = 0; mi < 4; ++mi)
#pragma unroll
                for (int nj = 0; nj < 8; ++nj)
                    acc[mi][nj] = __builtin_amdgcn_mfma_f32_16x16x32_bf16(
                        af[mi], bfr[nj], acc[mi][nj], 0, 0, 0);
        }
        __builtin_amdgcn_s_barrier();
        cur ^= 1;
    }

    // epilogue
#pragma unroll
    for (int nj = 0; nj < 8; ++nj) {
        int col = n0 + wc * 128 + nj * 16 + li;
        float bv;
        if (EPI == 5) bv = (col < D_) ? bias[col] : bias2[col - D_];
        else bv = bias[col];
#pragma unroll
        for (int mi = 0; mi < 4; ++mi) {
#pragma unroll
            for (int rg = 0; rg < 4; ++rg) {
                int grow = m0 + wr * 64 + mi * 16 + 4 * lg + rg;
                float v = acc[mi][nj][rg] + bv;
                if (EPI == 3) {
                    float u = 0.7978845608028654f * v * (1.f + 0.044715f * v * v);
                    u = fminf(fmaxf(u, -15.f), 15.f);
                    float e = __expf(2.f * u);
                    float th = (e - 1.f) / (e + 1.f);
                    ((u16*)out)[(size_t)grow * (size_t)Nn + col] = f2bf(0.5f * v * (1.f + th));
                } else {   // EPI == 5
                    int b = grow >> 10, n = grow & 1023;
                    if (n0 < 1024) {
                        int hd = col >> 6, dh = col & 63;
                        ((u16*)out)[(((size_t)(b * H_ + hd)) * N_ + n) * DH_ + dh] = f2bf(v);
                    } else if (n0 < 2048) {
                        int c2 = col - 1024;
                        int hd = c2 >> 6, dh = c2 & 63;
                        ((u16*)out)[4194304u + (((size_t)(b * H_ + hd)) * N_ + n) * DH_ + dh] =
                            f2bf(v);
                    } else {
                        int c2 = col - 2048;
                        int hd = c2 >> 6, dh = c2 & 63;
                        ((u16*)out)[8388608u + (((size_t)(b * H_ + hd)) * DH_ + dh) * N_ + n] =
                            f2bf(v);
                    }
                }
            }
        }
    }
}

// ---------------- flash attention: 4 warps x 32 q-rows, 32x32 MFMA, swapped -------
__global__ __launch_bounds__(256) void attn2(const u16* __restrict__ q,
                                             const u16* __restrict__ k,
                                             const u16* __restrict__ vt,
                                             u16* __restrict__ o) {
    __shared__ __align__(16) char qs[16384];       // Q tile [128 q][64 dh], later O
    __shared__ __align__(16) char kv[2][16384];    // K [64 key][64 dh] | VT [64 d][64 key]
    const int tid = threadIdx.x, w = tid >> 6, lane = tid & 63;
    const int l31 = lane & 31, hi = lane >> 5;
    const int flat = blockIdx.x;                   // 512
    const int wgs = (flat & 7) * 64 + (flat >> 3);
    const int bh = wgs >> 3, qt = wgs & 7;
    const size_t base = (size_t)bh * (N_ * DH_);
    const int q0 = qt * 128;

#pragma unroll
    for (int j = 0; j < 4; ++j) {
        int basec = j * 256 + w * 64;
        int idx = basec + lane;
        int row = idx >> 3, cc = idx & 7;
        gload16(q + base + (size_t)(q0 + row) * DH_ + ((cc ^ (row & 7)) << 3),
                qs + basec * 16);
    }
    auto STAGEKV = [&](int t, char* buf) {
#pragma unroll
        for (int j = 0; j < 4; ++j) {
            int basec = j * 256 + w * 64;
            int idx = basec + lane;
            if (idx < 512) {
                int row = idx >> 3, cc = idx & 7;
                gload16(k + base + (size_t)(t * 64 + row) * DH_ + ((cc ^ (row & 7)) << 3),
                        buf + basec * 16);
            } else {
                int i2 = idx - 512;
                int row = i2 >> 3, cc = i2 & 7;
                gload16(vt + base + (size_t)row * N_ + t * 64 + ((cc ^ (row & 7)) << 3),
                        buf + basec * 16);
            }
        }
    };
    STAGEKV(0, kv[0]);
    __syncthreads();

    s16x8 qf[4];
    const int qr = w * 32 + l31;
#pragma unroll
    for (int st = 0; st < 4; ++st)
        qf[st] = *(const s16x8*)(qs + qr * 128 + (((st * 2 + hi) ^ (qr & 7)) << 4));

    f32x16 oa[2];
#pragma unroll
    for (int r = 0; r < 16; ++r) { oa[0][r] = 0.f; oa[1][r] = 0.f; }
    float mrow = -3e38f, lrow = 0.f;
    const float CSC = 0.125f * 1.44269504088896f;   // scale * log2(e)

    int cur = 0;
    for (int t = 0; t < 16; ++t) {
        if (t + 1 < 16) { STAGEKV(t + 1, kv[cur ^ 1]); WAITV(4); }
        else WAITV(0);
        __builtin_amdgcn_s_barrier();
        __builtin_amdgcn_sched_barrier(0);
        const char* Kb = kv[cur];
        const char* Vb = kv[cur] + 8192;

        f32x16 s[2];
#pragma unroll
        for (int r = 0; r < 16; ++r) { s[0][r] = 0.f; s[1][r] = 0.f; }
#pragma unroll
        for (int st = 0; st < 4; ++st) {
#pragma unroll
            for (int ks = 0; ks < 2; ++ks) {
                int r = ks * 32 + l31;
                s16x8 ka = *(const s16x8*)(Kb + r * 128 + (((st * 2 + hi) ^ (r & 7)) << 4));
                s[ks] = __builtin_amdgcn_mfma_f32_32x32x16_bf16(ka, qf[st], s[ks], 0, 0, 0);
            }
        }

        float tmax = s[0][0];
#pragma unroll
        for (int r = 1; r < 16; ++r) tmax = fmaxf(tmax, s[0][r]);
#pragma unroll
        for (int r = 0; r < 16; ++r) tmax = fmaxf(tmax, s[1][r]);
        tmax = fmaxf(tmax, __shfl_xor(tmax, 32));
        float mn = fmaxf(mrow, tmax);
        float al = __builtin_amdgcn_exp2f((mrow - mn) * CSC);
        float nmc = -mn * CSC;
        float rs0 = 0.f, rs1 = 0.f;
#pragma unroll
        for (int r = 0; r < 16; ++r) {
            float p0 = __builtin_amdgcn_exp2f(fmaf(s[0][r], CSC, nmc));
            float p1 = __builtin_amdgcn_exp2f(fmaf(s[1][r], CSC, nmc));
            s[0][r] = p0; s[1][r] = p1;
            rs0 += p0; rs1 += p1;
        }
        float rs = rs0 + rs1;
        rs += __shfl_xor(rs, 32);
        lrow = lrow * al + rs;
        mrow = mn;
#pragma unroll
        for (int r = 0; r < 16; ++r) { oa[0][r] *= al; oa[1][r] *= al; }

        unsigned u[16];
#pragma unroll
        for (int ks = 0; ks < 2; ++ks)
#pragma unroll
            for (int j = 0; j < 4; ++j) {
                u[ks * 8 + 2 * j]     = cvtpk(s[ks][4 * j + 0], s[ks][4 * j + 1]);
                u[ks * 8 + 2 * j + 1] = cvtpk(s[ks][4 * j + 2], s[ks][4 * j + 3]);
            }

#pragma unroll
        for (int kstep = 0; kstep < 4; ++kstep) {
            unsigned b0 = u[kstep * 4 + 0], b1 = u[kstep * 4 + 1];
            unsigned b2 = u[kstep * 4 + 2], b3 = u[kstep * 4 + 3];
            asm volatile("v_permlane32_swap_b32 %0, %1" : "+v"(b0), "+v"(b2));
            asm volatile("v_permlane32_swap_b32 %0, %1" : "+v"(b1), "+v"(b3));
            u32x4 pbu = (u32x4){b0, b1, b2, b3};
            s16x8 pb = __builtin_bit_cast(s16x8, pbu);
#pragma unroll
            for (int ds = 0; ds < 2; ++ds) {
                int r = ds * 32 + l31;
                s16x8 va = *(const s16x8*)(Vb + r * 128 + (((kstep * 2 + hi) ^ (r & 7)) << 4));
                oa[ds] = __builtin_amdgcn_mfma_f32_32x32x16_bf16(va, pb, oa[ds], 0, 0, 0);
            }
        }
        __builtin_amdgcn_s_barrier();
        cur ^= 1;
    }

    float inv = 1.f / lrow;
#pragma unroll
    for (int ds = 0; ds < 2; ++ds)
#pragma unroll
        for (int j = 0; j < 4; ++j)
#pragma unroll
            for (int t2 = 0; t2 < 2; ++t2) {
                unsigned pk = cvtpk(oa[ds][4 * j + 2 * t2] * inv,
                                    oa[ds][4 * j + 2 * t2 + 1] * inv);
                int row = qr;
                int dch = 4 * ds + j;
                *(unsigned*)(qs + row * 128 + ((dch ^ (row & 7)) << 4) +
                             (4 * hi + 2 * t2) * 2) = pk;
            }
    __syncthreads();
    {
        int r = tid >> 1, h2 = tid & 1;
        const int b = bh >> 4, hd = bh & 15;
        size_t obase = ((size_t)(b * N_ + q0 + r)) * D_ + hd * DH_;
#pragma unroll
        for (int c = 0; c < 4; ++c) {
            int c2 = h2 * 4 + c;
            s16x8 v = *(const s16x8*)(qs + r * 128 + ((c2 ^ (r & 7)) << 4));
            *(s16x8*)(o + obase + c2 * 8) = v;
        }
    }
}

// ---------------------------------------------------------------------------------
extern "C" void kernel_launch(void* const* d_in, const int* in_sizes, int n_in,
                              void* d_out, int out_size, void* d_ws, size_t ws_size,
                              hipStream_t stream) {
    const float* x    = (const float*)d_in[0];
    const float* c    = (const float*)d_in[1];
    const float* Wq   = (const float*)d_in[2];
    const float* bq   = (const float*)d_in[3];
    const float* Wkv  = (const float*)d_in[4];
    const float* bkv  = (const float*)d_in[5];
    const float* Wo   = (const float*)d_in[6];
    const float* bo   = (const float*)d_in[7];
    const float* W1   = (const float*)d_in[8];
    const float* b1   = (const float*)d_in[9];
    const float* W2   = (const float*)d_in[10];
    const float* b2   = (const float*)d_in[11];
    const float* Wada = (const float*)d_in[12];
    const float* bada = (const float*)d_in[13];

    char* ws = (char*)d_ws;
    const size_t MB = 1024 * 1024;
    u16*   wqkvT = (u16*)(ws + 0);       // 6MB: [3D][D] = Wq^T | Wkv^T
    u16*   woT  = (u16*)(ws + 6 * MB);   // 2MB
    u16*   w1T  = (u16*)(ws + 8 * MB);   // 8MB
    u16*   w2T  = (u16*)(ws + 16 * MB);  // 8MB
    float* mod  = (float*)(ws + 24 * MB);// 96KB
    u16*   h    = (u16*)(ws + 25 * MB);  // 8MB (h, later h2)
    u16*   qb   = (u16*)(ws + 33 * MB);  // 24MB: q | k(+4M elems) | vt(+8M elems)
    u16*   ao   = (u16*)(ws + 57 * MB);  // 8MB
    float* x1   = (float*)(ws + 65 * MB);// 16MB
    u16*   m1   = (u16*)(ws + 33 * MB);  // 32MB, reuses qkv+ao (dead by then)
    float* outp = (float*)d_out;

    transpose_all<<<12288, 256, 0, stream>>>(Wq, Wkv, Wo, W1, W2, wqkvT, woT, w1T, w2T);

    modk<<<dim3(24, 4), 256, 0, stream>>>(c, Wada, bada, mod);
    ln_mod<<<M_, 256, 0, stream>>>(x, mod, 0, 1, h);

    // fused qkv projection, 256^2 tiles: grid 16m x 12n = 192 blocks, chunks 4x6
    gemm256<5><<<192, 512, 0, stream>>>(h, wqkvT, bq, bkv, qb, M_, 3 * D_, D_, 4, 6);

    attn2<<<512, 256, 0, stream>>>(qb, qb + 4194304, qb + 8388608, ao);

    gemm_bt<2><<<dim3(8, 32), 256, 0, stream>>>(ao, woT, bo, x1, x, mod, M_, D_, D_, 2);

    ln_mod<<<M_, 256, 0, stream>>>(x1, mod, 3, 4, h);

    // W1, 256^2 tiles: grid 16 x 16 = 256 blocks, chunks 4x8
    gemm256<3><<<256, 512, 0, stream>>>(h, w1T, b1, nullptr, m1, M_, 4 * D_, D_, 4, 8);
    gemm_bt<4><<<dim3(8, 32), 256, 0, stream>>>(m1, w2T, b2, outp, x1, mod, M_, D_, 4 * D_, 5);
}